// Round 10
// baseline (2603.942 us; speedup 1.0000x reference)
//
#include <hip/hip_runtime.h>
#include <math.h>

// ---- problem constants ----
constexpr int Bv = 2, Tv = 2048, NTv = 512;
constexpr int DIMv = 768, DEPTHv = 8, MELv = 100, TDIMv = 512;
constexpr int DINNER = 1536, NSv = 128, PHv = 64, QQv = 64;
constexpr int NHv = DINNER / PHv;              // 24
constexpr int CONVD = DINNER + 2 * NSv;        // 1792
constexpr int DINP = 2 * DINNER + 2 * NSv + NHv; // 3352
constexpr int KCONVv = 4, FFIv = 2 * DIMv;     // 1536
constexpr int CNv = Tv / QQv;                  // 32
constexpr int PCK = 1504;                      // 31*48 padded
constexpr int KCAT = 768;                      // 712 padded to 64-mult

typedef unsigned short u16;
typedef unsigned int u32;
typedef __attribute__((ext_vector_type(8))) short short8v;
typedef __attribute__((ext_vector_type(4))) float f32x4;

__device__ __forceinline__ float siluf(float x) { return x / (1.f + expf(-x)); }
__device__ __forceinline__ float softplusf(float x) { return x > 20.f ? x : log1pf(expf(x)); }
__device__ __forceinline__ float mishf(float x) { return x * tanhf(softplusf(x)); }

__device__ __forceinline__ u16 f2bf(float v) {
    u32 u = __builtin_bit_cast(u32, v);
    u32 r = (u + 0x7fffu + ((u >> 16) & 1u)) >> 16;
    return (u16)r;
}
__device__ __forceinline__ float bf2f(u16 v) {
    u32 u = (u32)v << 16;
    return __builtin_bit_cast(float, u);
}
__device__ __forceinline__ float bf2fs(short v) { return bf2f((u16)v); }

__device__ __forceinline__ void gload16(const void* g, void* l) {
    __builtin_amdgcn_global_load_lds(
        (const __attribute__((address_space(1))) u32*)g,
        (__attribute__((address_space(3))) u32*)l, 16, 0, 0);
}

__device__ __forceinline__ float blockReduceSum(float v) {
    __shared__ float red[4];
    #pragma unroll
    for (int off = 32; off > 0; off >>= 1) v += __shfl_down(v, off, 64);
    __syncthreads();
    if ((threadIdx.x & 63) == 0) red[threadIdx.x >> 6] = v;
    __syncthreads();
    return red[0] + red[1] + red[2] + red[3];
}

// ================== GEMM epilogue (shared) ==================
template <int EPI>
__device__ __forceinline__ void gemm_epi(f32x4* acc, int row, int col,
        int N, int ldc, const float* bias, float* Cf, u16* Cb,
        const float* modv, int goff, int mstride) {
    if (col >= N) return;
    const float bv = (EPI == 1 || EPI == 2 || EPI == 4) ? bias[col] : 0.f;
    #pragma unroll
    for (int r = 0; r < 4; r++) {
        float v = (*acc)[r] + bv;
        if (EPI == 0) {
            Cb[(size_t)(row + r) * ldc + col] = f2bf(v);
        } else if (EPI == 2) {
            float xx = v;
            v = 0.5f * xx * (1.f + tanhf(0.7978845608028654f * (xx + 0.044715f * xx * xx * xx)));
            Cb[(size_t)(row + r) * ldc + col] = f2bf(v);
        } else if (EPI == 3 || EPI == 4) {
            const int bb = (row + r) >> 11;   // row / Tv
            float g = modv[(size_t)bb * mstride + goff + col];
            Cf[(size_t)(row + r) * ldc + col] += g * v;
        } else {
            Cf[(size_t)(row + r) * ldc + col] = v;
        }
    }
}

// ---- bf16 MFMA GEMM, BM=128/BN=128/BK=32, 2-phase dbuf, XCD-swizzled ----
template <int EPI>
__global__ __launch_bounds__(256) void gemm_bf16(const u16* __restrict__ A,
        const u16* __restrict__ BT, const float* __restrict__ bias,
        float* __restrict__ Cf, u16* __restrict__ Cb,
        int M, int N, int K, int ldc,
        const float* __restrict__ modv, int goff, int mstride) {
    __shared__ __align__(16) u16 As[2][128 * 32];
    __shared__ __align__(16) u16 Bs[2][128 * 32];
    const int tid = threadIdx.x;
    const int gx = gridDim.x;
    const int nwg = gx * gridDim.y;
    int flat = blockIdx.y * gx + blockIdx.x;
    const int qq = nwg >> 3;
    flat = (flat & 7) * qq + (flat >> 3);
    const int m0 = (flat / gx) * 128, n0 = (flat % gx) * 128;
    const int lane = tid & 63;
    const int wid = tid >> 6;
    const int wm = (wid >> 1) * 64, wn = (wid & 1) * 64;
    f32x4 acc[4][4] = {};
    const int srow = tid >> 2, sseg = (tid & 3) * 8;
    const u16* Ag = A + (size_t)(m0 + srow) * K + sseg;
    const u16* Bg = BT + (size_t)(n0 + srow) * K + sseg;
    const int lr = lane & 15, lk = (lane >> 4) * 8;
    gload16(Ag, &As[0][tid * 8]);
    gload16(Ag + (size_t)64 * K, &As[0][tid * 8 + 64 * 32]);
    gload16(Bg, &Bs[0][tid * 8]);
    gload16(Bg + (size_t)64 * K, &Bs[0][tid * 8 + 64 * 32]);
    __syncthreads();
    int cur = 0;
    for (int k0 = 0; k0 < K; k0 += 32) {
        if (k0 + 32 < K) {
            const int nb = cur ^ 1, kn = k0 + 32;
            gload16(Ag + kn, &As[nb][tid * 8]);
            gload16(Ag + kn + (size_t)64 * K, &As[nb][tid * 8 + 64 * 32]);
            gload16(Bg + kn, &Bs[nb][tid * 8]);
            gload16(Bg + kn + (size_t)64 * K, &Bs[nb][tid * 8 + 64 * 32]);
        }
        short8v a_f[4], b_f[4];
        #pragma unroll
        for (int i = 0; i < 4; i++)
            a_f[i] = *(const short8v*)&As[cur][(wm + i * 16 + lr) * 32 + lk];
        #pragma unroll
        for (int j = 0; j < 4; j++)
            b_f[j] = *(const short8v*)&Bs[cur][(wn + j * 16 + lr) * 32 + lk];
        #pragma unroll
        for (int i = 0; i < 4; i++)
            #pragma unroll
            for (int j = 0; j < 4; j++)
                acc[i][j] = __builtin_amdgcn_mfma_f32_16x16x32_bf16(a_f[i], b_f[j], acc[i][j], 0, 0, 0);
        __syncthreads();
        cur ^= 1;
    }
    const int r0 = (lane >> 4) * 4;
    #pragma unroll
    for (int i = 0; i < 4; i++)
        #pragma unroll
        for (int j = 0; j < 4; j++)
            gemm_epi<EPI>(&acc[i][j], m0 + wm + i * 16 + r0, n0 + wn + j * 16 + lr,
                          N, ldc, bias, Cf, Cb, modv, goff, mstride);
}

// ---- small bf16 GEMM: BM=64/BN=128/BK=32, 2-phase dbuf (24KB LDS), XCD-swizzled ----
template <int EPI>
__global__ __launch_bounds__(256) void gemm_bf16s(const u16* __restrict__ A,
        const u16* __restrict__ BT, const float* __restrict__ bias,
        float* __restrict__ Cf, u16* __restrict__ Cb,
        int M, int N, int K, int ldc,
        const float* __restrict__ modv, int goff, int mstride) {
    __shared__ __align__(16) u16 As[2][64 * 32];
    __shared__ __align__(16) u16 Bs[2][128 * 32];
    const int tid = threadIdx.x;
    const int gx = gridDim.x;
    const int nwg = gx * gridDim.y;
    int flat = blockIdx.y * gx + blockIdx.x;
    const int qq = nwg >> 3;
    flat = (flat & 7) * qq + (flat >> 3);
    const int m0 = (flat / gx) * 64, n0 = (flat % gx) * 128;
    const int lane = tid & 63;
    const int wid = tid >> 6;
    const int wn = wid * 32;
    f32x4 acc[4][2] = {};
    const int srow = tid >> 2, sseg = (tid & 3) * 8;
    const u16* Ag = A + (size_t)(m0 + srow) * K + sseg;
    const u16* Bg = BT + (size_t)(n0 + srow) * K + sseg;
    const int lr = lane & 15, lk = (lane >> 4) * 8;
    gload16(Ag, &As[0][tid * 8]);
    gload16(Bg, &Bs[0][tid * 8]);
    gload16(Bg + (size_t)64 * K, &Bs[0][tid * 8 + 64 * 32]);
    __syncthreads();
    int cur = 0;
    for (int k0 = 0; k0 < K; k0 += 32) {
        if (k0 + 32 < K) {
            const int nb = cur ^ 1, kn = k0 + 32;
            gload16(Ag + kn, &As[nb][tid * 8]);
            gload16(Bg + kn, &Bs[nb][tid * 8]);
            gload16(Bg + kn + (size_t)64 * K, &Bs[nb][tid * 8 + 64 * 32]);
        }
        short8v a_f[4], b_f[2];
        #pragma unroll
        for (int i = 0; i < 4; i++)
            a_f[i] = *(const short8v*)&As[cur][(i * 16 + lr) * 32 + lk];
        #pragma unroll
        for (int j = 0; j < 2; j++)
            b_f[j] = *(const short8v*)&Bs[cur][(wn + j * 16 + lr) * 32 + lk];
        #pragma unroll
        for (int i = 0; i < 4; i++)
            #pragma unroll
            for (int j = 0; j < 2; j++)
                acc[i][j] = __builtin_amdgcn_mfma_f32_16x16x32_bf16(a_f[i], b_f[j], acc[i][j], 0, 0, 0);
        __syncthreads();
        cur ^= 1;
    }
    const int r0 = (lane >> 4) * 4;
    #pragma unroll
    for (int i = 0; i < 4; i++)
        #pragma unroll
        for (int j = 0; j < 2; j++)
            gemm_epi<EPI>(&acc[i][j], m0 + i * 16 + r0, n0 + wn + j * 16 + lr,
                          N, ldc, bias, Cf, Cb, modv, goff, mstride);
}

// ---- batched weight convert: f32 [Kmax,N] (per layer) -> bf16 [Npad,Kd] ----
__global__ __launch_bounds__(256) void wt_convert_b(const float* __restrict__ W,
        u16* __restrict__ WT, int Kd, int N, int Kmax, int Npad) {
    const float* Wl = W + (size_t)blockIdx.z * Kmax * N;
    u16* WTl = WT + (size_t)blockIdx.z * Npad * Kd;
    __shared__ float t[32][33];
    const int n0 = blockIdx.x * 32, k0 = blockIdx.y * 32;
    const int c = threadIdx.x & 31, rq = (threadIdx.x >> 5) * 4;
    #pragma unroll
    for (int i = 0; i < 4; i++) {
        int n = n0 + c, k = k0 + rq + i;
        t[rq + i][c] = (n < N && k < Kmax) ? Wl[(size_t)k * N + n] : 0.f;
    }
    __syncthreads();
    #pragma unroll
    for (int i = 0; i < 4; i++)
        WTl[(size_t)(n0 + rq + i) * Kd + k0 + c] = f2bf(t[c][rq + i]);
}

// ---- pos-conv weight: w[31][48][768] -> WT[768][1504] bf16 ----
__global__ __launch_bounds__(256) void pw_convert(const float* __restrict__ w,
        u16* __restrict__ WT) {
    __shared__ float t[32][33];
    const int kk0 = blockIdx.x * 32, o0 = blockIdx.y * 32;
    const int c = threadIdx.x & 31, rq = (threadIdx.x >> 5) * 4;
    #pragma unroll
    for (int i = 0; i < 4; i++) {
        int kk = kk0 + rq + i;
        t[rq + i][c] = (kk < 1488) ? w[(size_t)kk * DIMv + o0 + c] : 0.f;
    }
    __syncthreads();
    #pragma unroll
    for (int i = 0; i < 4; i++)
        WT[(size_t)(o0 + rq + i) * PCK + kk0 + c] = f2bf(t[c][rq + i]);
}

// ---- grouped conv K=31 via implicit-im2col MFMA ----
template <int IN_BF, int FUSE>
__global__ __launch_bounds__(256) void posconv_mfma(const void* __restrict__ inv,
        const u16* __restrict__ WT, const float* __restrict__ bias,
        void* __restrict__ outv) {
    __shared__ __align__(16) u16 xs[95 * 48];
    const int t0 = blockIdx.x * 64, g = blockIdx.y, b = blockIdx.z;
    const int tid = threadIdx.x;
    for (int e = tid; e < 95 * 48; e += 256) {
        int rr = e / 48, cc = e % 48;
        int t = t0 - 15 + rr;
        float v = 0.f;
        if (t >= 0 && t < Tv) {
            size_t gi = ((size_t)b * Tv + t) * DIMv + g * 48 + cc;
            v = IN_BF ? bf2f(((const u16*)inv)[gi]) : ((const float*)inv)[gi];
        }
        xs[e] = f2bf(v);
    }
    __syncthreads();
    const int lane = tid & 63, w = tid >> 6;
    const int lr = lane & 15, lq8 = (lane >> 4) * 8, rq = (lane >> 4) * 4;
    const u16* arow = &xs[(w * 16 + lr) * 48 + lq8];
    const u16* brow = &WT[(size_t)(g * 48 + lr) * PCK + lq8];
    f32x4 acc[3] = {};
    #pragma unroll 2
    for (int ks = 0; ks < PCK / 32; ks++) {
        short8v a = *(const short8v*)(arow + ks * 32);
        #pragma unroll
        for (int j = 0; j < 3; j++) {
            short8v bf = *(const short8v*)(brow + (size_t)j * 16 * PCK + ks * 32);
            acc[j] = __builtin_amdgcn_mfma_f32_16x16x32_bf16(a, bf, acc[j], 0, 0, 0);
        }
    }
    #pragma unroll
    for (int j = 0; j < 3; j++) {
        const int o = g * 48 + j * 16 + lr;
        const float bvv = bias[o];
        #pragma unroll
        for (int r = 0; r < 4; r++) {
            const int t = t0 + w * 16 + rq + r;
            float v = acc[j][r] + bvv;
            size_t gi = ((size_t)b * Tv + t) * DIMv + o;
            if (FUSE == 0) ((u16*)outv)[gi] = f2bf(mishf(v));
            else ((float*)outv)[gi] += mishf(v);
        }
    }
}

// ---- time embedding stage 1 ----
__global__ __launch_bounds__(256) void temb1_kernel(const float* __restrict__ timev,
        const float* __restrict__ t_w1, const float* __restrict__ t_b1,
        float* __restrict__ hid) {
    const int b = blockIdx.y;
    const int o = blockIdx.x * 64 + (threadIdx.x & 63);
    const int ks = threadIdx.x >> 6;
    __shared__ float te[256];
    __shared__ float part[4][64];
    {
        int j = threadIdx.x, f = j & 127;
        float fr = expf(-logf(10000.f) / 127.f * (float)f);
        float ang = 1000.f * timev[b] * fr;
        te[j] = (j < 128) ? sinf(ang) : cosf(ang);
    }
    __syncthreads();
    float acc = 0.f;
    #pragma unroll 8
    for (int k = ks * 64; k < ks * 64 + 64; k++) acc += te[k] * t_w1[(size_t)k * DIMv + o];
    part[ks][threadIdx.x & 63] = acc;
    __syncthreads();
    if (threadIdx.x < 64) {
        float r = part[0][threadIdx.x] + part[1][threadIdx.x] + part[2][threadIdx.x] + part[3][threadIdx.x]
                + t_b1[o];
        hid[b * DIMv + o] = siluf(r);
    }
}

// ---- time embedding stage 2 ----
__global__ __launch_bounds__(256) void temb2_kernel(const float* __restrict__ hid,
        const float* __restrict__ t_w2, const float* __restrict__ t_b2,
        float* __restrict__ st_out) {
    const int b = blockIdx.y;
    const int o = blockIdx.x * 64 + (threadIdx.x & 63);
    const int ks = threadIdx.x >> 6;
    __shared__ float hv[DIMv];
    __shared__ float part[4][64];
    for (int j = threadIdx.x; j < DIMv; j += 256) hv[j] = hid[b * DIMv + j];
    __syncthreads();
    float acc = 0.f;
    #pragma unroll 8
    for (int k = ks * 192; k < ks * 192 + 192; k++) acc += hv[k] * t_w2[(size_t)k * DIMv + o];
    part[ks][threadIdx.x & 63] = acc;
    __syncthreads();
    if (threadIdx.x < 64) {
        float r = part[0][threadIdx.x] + part[1][threadIdx.x] + part[2][threadIdx.x] + part[3][threadIdx.x]
                + t_b2[o];
        st_out[b * DIMv + o] = siluf(r);
    }
}

// ---- batched modulation vectors ----
__global__ __launch_bounds__(256) void modvec_kernel(const float* __restrict__ st,
        const float* __restrict__ W, const float* __restrict__ bias,
        float* __restrict__ out, int N) {
    const int l = blockIdx.z, b = blockIdx.y;
    const int o = blockIdx.x * 64 + (threadIdx.x & 63);
    const int ks = threadIdx.x >> 6;
    __shared__ float sv[DIMv];
    __shared__ float part[4][64];
    for (int j = threadIdx.x; j < DIMv; j += 256) sv[j] = st[b * DIMv + j];
    __syncthreads();
    const float* Wl = W + (size_t)l * DIMv * N + o;
    float acc = 0.f;
    #pragma unroll 8
    for (int k = ks * 192; k < ks * 192 + 192; k++) acc += sv[k] * Wl[(size_t)k * N];
    part[ks][threadIdx.x & 63] = acc;
    __syncthreads();
    if (threadIdx.x < 64) {
        float r = part[0][threadIdx.x] + part[1][threadIdx.x] + part[2][threadIdx.x] + part[3][threadIdx.x]
                + bias[(size_t)l * N + o];
        out[((size_t)l * Bv + b) * N + o] = r;
    }
}

// ---- concat [x, cond, temb] -> bf16, K-padded to 768 ----
__global__ void concat_bf16(const float* __restrict__ x, const float* __restrict__ cond,
                            const float* __restrict__ table, const int* __restrict__ text,
                            u16* __restrict__ cat) {
    size_t i = (size_t)blockIdx.x * 256 + threadIdx.x;
    const size_t total = (size_t)Bv * Tv * KCAT;
    if (i >= total) return;
    int j = (int)(i % KCAT);
    size_t row = i / KCAT;
    int t = (int)(row % Tv), b = (int)(row / Tv);
    float v = 0.f;
    if (j < MELv) v = x[row * MELv + j];
    else if (j < 2 * MELv) v = cond[row * MELv + (j - MELv)];
    else if (j < 712) {
        int idx = (t < NTv) ? (text[b * NTv + t] + 1) : 0;
        v = table[(size_t)idx * TDIMv + (j - 2 * MELv)];
    }
    cat[i] = f2bf(v);
}

// ---- LayerNorm with adaLN modulation; BF=1 writes bf16 ----
template <int BF>
__global__ __launch_bounds__(256) void ln_mod_kernel(const float* __restrict__ h,
        void* __restrict__ outv, const float* __restrict__ modv,
        int sc_off, int sh_off, int mod_stride) {
    const int row = blockIdx.x;
    const int b = row / Tv;
    const float* hr = h + (size_t)row * DIMv;
    float s = 0.f;
    for (int j = threadIdx.x; j < DIMv; j += 256) s += hr[j];
    s = blockReduceSum(s);
    const float m = s / DIMv;
    float v = 0.f;
    for (int j = threadIdx.x; j < DIMv; j += 256) { float d = hr[j] - m; v += d * d; }
    v = blockReduceSum(v);
    const float rstd = rsqrtf(v / DIMv + 1e-6f);
    const float* mb = modv + (size_t)b * mod_stride;
    for (int j = threadIdx.x; j < DIMv; j += 256) {
        float val = (hr[j] - m) * rstd * (1.f + mb[sc_off + j]) + mb[sh_off + j];
        if (BF) ((u16*)outv)[(size_t)row * DIMv + j] = f2bf(val);
        else ((float*)outv)[(size_t)row * DIMv + j] = val;
    }
}

// ---- merged SSD front: x-transpose dwconv (blocks 0..23) + BC dwconv/CB/BT (block 24) ----
__global__ __launch_bounds__(256) void ssd_front(const u16* __restrict__ zxb,
        const float* __restrict__ cw, const float* __restrict__ cbv,
        u16* __restrict__ xT, u16* __restrict__ xbcBC,
        float* __restrict__ CBg, u16* __restrict__ BTg) {
    constexpr int ST = 136;
    __shared__ __align__(16) u16 smem[64 * ST * 2];   // 34.8KB, carved by both paths
    const int sel = blockIdx.x;
    const int c = blockIdx.y, b = blockIdx.z;
    const int bc = b * CNv + c;
    const int tid = threadIdx.x;
    const size_t rowbase = (size_t)b * Tv + (size_t)c * QQv;
    if (sel < 24) {
        // ---- dwconvT path: transpose-conv 64 x-channels ----
        u16* in_s = smem;                 // [67][72]
        const int pb = sel;
        for (int e = tid; e < 67 * 8; e += 256) {
            int sp = e >> 3, p8 = (e & 7) * 8;
            int t = c * 64 + sp - 3;
            short8v v = {};
            if (t >= 0)
                v = *(const short8v*)&zxb[((size_t)b * Tv + t) * DINP + DINNER + pb * 64 + p8];
            *(short8v*)&in_s[sp * 72 + p8] = v;
        }
        __syncthreads();
        const int p = tid >> 2, sb = (tid & 3) * 16;
        const int ch = pb * 64 + p;
        const float w0 = cw[ch * 4], w1 = cw[ch * 4 + 1], w2 = cw[ch * 4 + 2], w3 = cw[ch * 4 + 3];
        const float bb = cbv[ch];
        short8v o0, o1;
        #pragma unroll
        for (int i = 0; i < 16; i++) {
            int s = sb + i;
            float acc = bb + bf2f(in_s[s * 72 + p]) * w0 + bf2f(in_s[(s + 1) * 72 + p]) * w1
                      + bf2f(in_s[(s + 2) * 72 + p]) * w2 + bf2f(in_s[(s + 3) * 72 + p]) * w3;
            short r = (short)f2bf(siluf(acc));
            if (i < 8) o0[i] = r; else o1[i - 8] = r;
        }
        u16* dst = xT + ((size_t)bc * DINNER + ch) * 64 + sb;
        *(short8v*)dst = o0;
        *(short8v*)(dst + 8) = o1;
    } else {
        // ---- BC path: fused dwconv+silu for B/C, CB = C.B^T, BT^T to global ----
        u16* Cs = smem;                   // [64][ST]
        u16* Bs = smem + 64 * ST;         // [64][ST]
        for (int e = tid; e < 64 * 32; e += 256) {
            int r = e >> 5, n8 = (e & 31) * 8;
            size_t row = rowbase + r;
            int t = c * 64 + r;
            const u16* base = zxb + row * DINP + DINNER + n8;
            float acc[8];
            #pragma unroll
            for (int u = 0; u < 8; u++) acc[u] = cbv[DINNER + n8 + u];
            #pragma unroll
            for (int k = 0; k < KCONVv; k++) {
                const int d = k - 3;
                if (t + d < 0) continue;
                short8v tv = *(const short8v*)(base + (ptrdiff_t)d * DINP);
                #pragma unroll
                for (int u = 0; u < 8; u++)
                    acc[u] += bf2fs(tv[u]) * cw[(DINNER + n8 + u) * KCONVv + k];
            }
            short8v o;
            #pragma unroll
            for (int u = 0; u < 8; u++) o[u] = (short)f2bf(siluf(acc[u]));
            if (n8 < NSv) *(short8v*)&Bs[r * ST + n8] = o;
            else *(short8v*)&Cs[r * ST + (n8 - NSv)] = o;
            *(short8v*)&xbcBC[row * 256 + n8] = o;
        }
        __syncthreads();
        u16* btg = BTg + (size_t)bc * (NSv * QQv);
        for (int e = tid; e < 128 * 64; e += 256) {
            int n = e >> 6, s = e & 63;
            btg[e] = Bs[s * ST + n];
        }
        const int lane = tid & 63, w = tid >> 6;
        const int lr = lane & 15, lk8 = (lane >> 4) * 8, rq = (lane >> 4) * 4;
        f32x4 acc[4] = {};
        #pragma unroll
        for (int ks = 0; ks < 4; ks++) {
            short8v a = *(const short8v*)&Cs[(w * 16 + lr) * ST + ks * 32 + lk8];
            #pragma unroll
            for (int j = 0; j < 4; j++) {
                short8v bf = *(const short8v*)&Bs[(j * 16 + lr) * ST + ks * 32 + lk8];
                acc[j] = __builtin_amdgcn_mfma_f32_16x16x32_bf16(a, bf, acc[j], 0, 0, 0);
            }
        }
        float* out = CBg + (size_t)bc * 4096;
        #pragma unroll
        for (int j = 0; j < 4; j++)
            #pragma unroll
            for (int r = 0; r < 4; r++)
                out[(w * 16 + rq + r) * 64 + j * 16 + lr] = acc[j][r];
    }
}

// ---- SSD part1: scan; y_in = Wsm' @ xT^T; S = (xT.dtrev) @ B  (S bf16) ----
__global__ __launch_bounds__(256) void ssd_part1m(const u16* __restrict__ xT,
        const u16* __restrict__ BTg, const u16* __restrict__ zxb,
        const float* __restrict__ dt_bias, const float* __restrict__ A_log,
        const float* __restrict__ CBg, u16* __restrict__ ybuf,
        u16* __restrict__ Sg, float* __restrict__ acg, float* __restrict__ atg) {
    constexpr int ST64 = 72;
    __shared__ __align__(16) u16 xTs[64 * ST64];   // [p][s]
    __shared__ __align__(16) u16 Wsm[64 * ST64];   // [q][s]  (cb*exp*dt)
    __shared__ __align__(16) u16 BTs[128 * ST64];  // [n][s]  (B^T * dt*erev)
    __shared__ float ac[64], dts[64], dtrev[64];
    const int h = blockIdx.x, c = blockIdx.y, b = blockIdx.z;
    const int bc = b * CNv + c;
    const int tid = threadIdx.x;
    const size_t rowbase = (size_t)b * Tv + (size_t)c * QQv;
    const size_t bch = ((size_t)bc) * NHv + h;
    if (tid < 64) {
        float raw = bf2f(zxb[(rowbase + tid) * DINP + DINNER + CONVD + h]) + dt_bias[h];
        float dtv = softplusf(raw);
        dts[tid] = dtv;
        float v = dtv * (-expf(A_log[h]));
        #pragma unroll
        for (int off = 1; off < 64; off <<= 1) {
            float t = __shfl_up(v, off, 64);
            if (tid >= off) v += t;
        }
        ac[tid] = v;
        float v63 = __shfl(v, 63, 64);
        dtrev[tid] = dtv * expf(v63 - v);
        acg[bch * 64 + tid] = v;
        if (tid == 63) atg[bch] = expf(v63);
    }
    {
        const u16* src = xT + ((size_t)bc * DINNER + h * PHv) * 64;
        for (int e = tid; e < 64 * 8; e += 256) {
            int p = e >> 3, s8 = (e & 7) * 8;
            *(short8v*)&xTs[p * ST64 + s8] = *(const short8v*)(src + p * 64 + s8);
        }
    }
    __syncthreads();
    {
        const u16* btg = BTg + (size_t)bc * (NSv * QQv);
        for (int e = tid; e < 128 * 8; e += 256) {
            int n = e >> 3, s8 = (e & 7) * 8;
            short8v v = *(const short8v*)(btg + n * 64 + s8);
            short8v o;
            #pragma unroll
            for (int u = 0; u < 8; u++)
                o[u] = (short)f2bf(bf2fs(v[u]) * dtrev[s8 + u]);
            *(short8v*)&BTs[n * ST64 + s8] = o;
        }
        const float* cbrow = CBg + (size_t)bc * 4096;
        for (int e = tid; e < 1024; e += 256) {
            int q = e >> 4, s4 = (e & 15) * 4;
            f32x4 cb4 = *(const f32x4*)&cbrow[q * 64 + s4];
            float aq = ac[q];
            #pragma unroll
            for (int u = 0; u < 4; u++) {
                int s = s4 + u;
                float wv = (s <= q) ? cb4[u] * expf(aq - ac[s]) * dts[s] : 0.f;
                Wsm[q * ST64 + s] = f2bf(wv);
            }
        }
    }
    __syncthreads();
    const int lane = tid & 63, w = tid >> 6;
    const int lr = lane & 15, lk8 = (lane >> 4) * 8, rq = (lane >> 4) * 4;
    // y_in[q][p]
    {
        f32x4 acc[4] = {};
        #pragma unroll
        for (int ks = 0; ks < 2; ks++) {
            short8v bf = *(const short8v*)&xTs[(w * 16 + lr) * ST64 + ks * 32 + lk8];
            #pragma unroll
            for (int i = 0; i < 4; i++) {
                short8v a = *(const short8v*)&Wsm[(i * 16 + lr) * ST64 + ks * 32 + lk8];
                acc[i] = __builtin_amdgcn_mfma_f32_16x16x32_bf16(a, bf, acc[i], 0, 0, 0);
            }
        }
        #pragma unroll
        for (int i = 0; i < 4; i++)
            #pragma unroll
            for (int r = 0; r < 4; r++) {
                int q = i * 16 + rq + r, p = w * 16 + lr;
                ybuf[(rowbase + q) * DINNER + h * PHv + p] = f2bf(acc[i][r]);
            }
    }
    // S[p][n]
    {
        f32x4 acc[4][2] = {};
        #pragma unroll
        for (int ks = 0; ks < 2; ks++) {
            short8v a[4];
            #pragma unroll
            for (int i = 0; i < 4; i++)
                a[i] = *(const short8v*)&xTs[(i * 16 + lr) * ST64 + ks * 32 + lk8];
            #pragma unroll
            for (int j = 0; j < 2; j++) {
                short8v bf = *(const short8v*)&BTs[(w * 32 + j * 16 + lr) * ST64 + ks * 32 + lk8];
                #pragma unroll
                for (int i = 0; i < 4; i++)
                    acc[i][j] = __builtin_amdgcn_mfma_f32_16x16x32_bf16(a[i], bf, acc[i][j], 0, 0, 0);
            }
        }
        u16* So = Sg + bch * (PHv * NSv);
        #pragma unroll
        for (int i = 0; i < 4; i++)
            #pragma unroll
            for (int j = 0; j < 2; j++)
                #pragma unroll
                for (int r = 0; r < 4; r++)
                    So[(i * 16 + rq + r) * NSv + w * 32 + j * 16 + lr] = f2bf(acc[i][j][r]);
    }
}

// ---- inter-chunk scan (bf16 storage, f32 accumulator) ----
__global__ void ssd_scan(u16* __restrict__ Sg, const float* __restrict__ atg) {
    int idx = blockIdx.x * 256 + threadIdx.x;
    if (idx >= Bv * NHv * PHv * NSv) return;
    int n = idx % NSv;
    int p = (idx / NSv) % PHv;
    int h = (idx / (NSv * PHv)) % NHv;
    int b = idx / (NSv * PHv * NHv);
    float H = 0.f;
    for (int c = 0; c < CNv; c++) {
        size_t bch = ((size_t)b * CNv + c) * NHv + h;
        size_t off = bch * PHv * NSv + (size_t)p * NSv + n;
        float s = bf2f(Sg[off]);
        float at = atg[bch];
        Sg[off] = f2bf(H);
        H = at * H + s;
    }
}

// ---- SSD part2: y += (C @ prev^T)*eac + D*x ----
__global__ __launch_bounds__(256) void ssd_part2m(const u16* __restrict__ xbcBC,
        const u16* __restrict__ xT, const u16* __restrict__ Sg,
        const float* __restrict__ acg, const float* __restrict__ Dp,
        u16* __restrict__ ybuf) {
    constexpr int ST = 136;
    __shared__ __align__(16) u16 Cs[64 * ST];
    __shared__ __align__(16) u16 Ps[64 * ST];
    __shared__ float eac[64];
    const int h = blockIdx.x, c = blockIdx.y, b = blockIdx.z;
    const int bc = b * CNv + c;
    const int tid = threadIdx.x;
    const size_t rowbase = (size_t)b * Tv + (size_t)c * QQv;
    const size_t bch = ((size_t)bc) * NHv + h;
    if (tid < 64) eac[tid] = expf(acg[bch * 64 + tid]);
    for (int e = tid; e < 64 * 16; e += 256) {
        int r = e >> 4, n8 = (e & 15) * 8;
        *(short8v*)&Cs[r * ST + n8] =
            *(const short8v*)&xbcBC[(rowbase + r) * 256 + NSv + n8];
        *(short8v*)&Ps[r * ST + n8] =
            *(const short8v*)&Sg[bch * (PHv * NSv) + (size_t)r * NSv + n8];
    }
    __syncthreads();
    const int lane = tid & 63, w = tid >> 6;
    const int lr = lane & 15, lk8 = (lane >> 4) * 8, rq = (lane >> 4) * 4;
    f32x4 acc[4] = {};
    #pragma unroll
    for (int ks = 0; ks < 4; ks++) {
        short8v bf = *(const short8v*)&Ps[(w * 16 + lr) * ST + ks * 32 + lk8];
        #pragma unroll
        for (int i = 0; i < 4; i++) {
            short8v a = *(const short8v*)&Cs[(i * 16 + lr) * ST + ks * 32 + lk8];
            acc[i] = __builtin_amdgcn_mfma_f32_16x16x32_bf16(a, bf, acc[i], 0, 0, 0);
        }
    }
    const float Dh = Dp[h];
    const int p = w * 16 + lr;
    const u16* xrow = xT + ((size_t)bc * DINNER + h * PHv + p) * 64;
    #pragma unroll
    for (int i = 0; i < 4; i++)
        #pragma unroll
        for (int r = 0; r < 4; r++) {
            int q = i * 16 + rq + r;
            size_t yi = (rowbase + q) * DINNER + h * PHv + p;
            float xv = bf2f(xrow[q]);
            ybuf[yi] = f2bf(bf2f(ybuf[yi]) + acc[i][r] * eac[q] + Dh * xv);
        }
}

// ---- gate by silu(z), RMS norm, * rms_w (bf16 in/out) ----
__global__ __launch_bounds__(256) void gate_rms_kernel(const u16* __restrict__ y,
        const u16* __restrict__ zxb, const float* __restrict__ rms_w,
        u16* __restrict__ yb) {
    const int row = blockIdx.x;
    const u16* yr = y + (size_t)row * DINNER;
    const u16* zr = zxb + (size_t)row * DINP;
    float vals[8];
    float ss = 0.f;
    const int tid = threadIdx.x;
    if (tid < 192) {
        short8v yv = *(const short8v*)(yr + tid * 8);
        short8v zv = *(const short8v*)(zr + tid * 8);
        #pragma unroll
        for (int u = 0; u < 8; u++) {
            float v = bf2fs(yv[u]) * siluf(bf2fs(zv[u]));
            vals[u] = v;
            ss += v * v;
        }
    }
    ss = blockReduceSum(ss);
    const float scale = rsqrtf(ss / DINNER + 1e-5f);
    if (tid < 192) {
        short8v outv;
        #pragma unroll
        for (int u = 0; u < 8; u++)
            outv[u] = (short)f2bf(vals[u] * scale * rms_w[tid * 8 + u]);
        *(short8v*)(yb + (size_t)row * DINNER + tid * 8) = outv;
    }
}

extern "C" void kernel_launch(void* const* d_in, const int* in_sizes, int n_in,
                              void* d_out, int out_size, void* d_ws, size_t ws_size,
                              hipStream_t stream) {
    int s3 = (in_sizes[3] == Bv * NTv) ? 1 : 0;
    const float* x      = (const float*)d_in[0];
    const float* cond   = (const float*)d_in[1];
    const float* timev  = (const float*)d_in[2];
    const int*   text   = (const int*)(s3 ? d_in[3] : d_in[32]);
    const float* table  = (const float*)d_in[3 + s3];
    const float* inp_w  = (const float*)d_in[4 + s3];
    const float* inp_b  = (const float*)d_in[5 + s3];
    const float* pos_w1 = (const float*)d_in[6 + s3];
    const float* pos_b1 = (const float*)d_in[7 + s3];
    const float* pos_w2 = (const float*)d_in[8 + s3];
    const float* pos_b2 = (const float*)d_in[9 + s3];
    const float* t_w1   = (const float*)d_in[10 + s3];
    const float* t_b1   = (const float*)d_in[11 + s3];
    const float* t_w2   = (const float*)d_in[12 + s3];
    const float* t_b2   = (const float*)d_in[13 + s3];
    const float* adaln_w= (const float*)d_in[14 + s3];
    const float* adaln_b= (const float*)d_in[15 + s3];
    const float* in_w   = (const float*)d_in[16 + s3];
    const float* conv_w = (const float*)d_in[17 + s3];
    const float* conv_b = (const float*)d_in[18 + s3];
    const float* dt_bias= (const float*)d_in[19 + s3];
    const float* A_log  = (const float*)d_in[20 + s3];
    const float* Dp     = (const float*)d_in[21 + s3];
    const float* rms_w  = (const float*)d_in[22 + s3];
    const float* out_w  = (const float*)d_in[23 + s3];
    const float* ff_w1  = (const float*)d_in[24 + s3];
    const float* ff_b1  = (const float*)d_in[25 + s3];
    const float* ff_w2  = (const float*)d_in[26 + s3];
    const float* ff_b2  = (const float*)d_in[27 + s3];
    const float* fin_w  = (const float*)d_in[28 + s3];
    const float* fin_b  = (const float*)d_in[29 + s3];
    const float* proj_w = (const float*)d_in[30 + s3];
    const float* proj_b = (const float*)d_in[31 + s3];

    // ---- workspace layout ----
    float* ws = (float*)d_ws;
    const size_t n_h = (size_t)Bv * Tv * DIMv;
    size_t off = 0;
    auto nx = [&](size_t n) { float* p = ws + off; off += n; return p; };
    float* h_   = nx(n_h);
    float* ac_  = nx((size_t)Bv * CNv * NHv * QQv);
    float* at_  = nx((size_t)Bv * CNv * NHv);
    float* CB_  = nx((size_t)Bv * CNv * QQv * QQv);
    float* st_  = nx((size_t)Bv * DIMv);
    float* hid_ = nx((size_t)Bv * DIMv);
    float* mod_ = nx((size_t)DEPTHv * Bv * 6 * DIMv);
    float* fm_  = nx((size_t)Bv * 2 * DIMv);
    off = (off + 15) & ~(size_t)15;
    u16* wtin_  = (u16*)(ws + off);
    u16* wtout_ = wtin_  + (size_t)DEPTHv * 3456 * 768;
    u16* wtff1_ = wtout_ + (size_t)DEPTHv * 768 * 1536;
    u16* wtff2_ = wtff1_ + (size_t)DEPTHv * 1536 * 768;
    u16* wtinp_ = wtff2_ + (size_t)DEPTHv * 768 * 1536;
    u16* wtprj_ = wtinp_ + (size_t)768 * KCAT;
    u16* pwt1_  = wtprj_ + (size_t)128 * 768;
    u16* pwt2_  = pwt1_  + (size_t)768 * PCK;
    u16* zxb_   = pwt2_  + (size_t)768 * PCK;     // 4096x3352
    u16* xbcBC_ = zxb_   + (size_t)4096 * DINP;   // 4096x256
    u16* xT_    = xbcBC_ + (size_t)4096 * 256;    // 64 x 1536 x 64
    u16* BTg_   = xT_    + (size_t)64 * DINNER * 64;  // 64 x 128 x 64
    u16* S_     = BTg_   + (size_t)64 * NSv * 64; // bf16 state
    u16* yb_    = S_     + (size_t)Bv * CNv * NHv * PHv * NSv;
    u16* xnb_   = yb_    + (size_t)4096 * 1536;   // 4096x768
    u16* actb_  = xnb_   + (size_t)4096 * 768;    // 4096x1536
    u16* xnb2_  = actb_  + (size_t)4096 * 1536;   // 4096x768
    u16* catb_  = xnb2_  + (size_t)4096 * 768;    // 4096x768

    const int MT = Bv * Tv;

    // ---- batched weight conversions (all layers upfront) ----
    wt_convert_b<<<dim3(3456 / 32, 768 / 32, DEPTHv), 256, 0, stream>>>(
        in_w, wtin_, 768, DINP, DIMv, 3456);
    wt_convert_b<<<dim3(768 / 32, 1536 / 32, DEPTHv), 256, 0, stream>>>(
        out_w, wtout_, 1536, DIMv, DINNER, 768);
    wt_convert_b<<<dim3(1536 / 32, 768 / 32, DEPTHv), 256, 0, stream>>>(
        ff_w1, wtff1_, 768, FFIv, DIMv, 1536);
    wt_convert_b<<<dim3(768 / 32, 1536 / 32, DEPTHv), 256, 0, stream>>>(
        ff_w2, wtff2_, 1536, DIMv, FFIv, 768);
    wt_convert_b<<<dim3(768 / 32, KCAT / 32, 1), 256, 0, stream>>>(
        inp_w, wtinp_, KCAT, DIMv, 712, 768);
    wt_convert_b<<<dim3(128 / 32, 768 / 32, 1), 256, 0, stream>>>(
        proj_w, wtprj_, 768, MELv, DIMv, 128);
    pw_convert<<<dim3(PCK / 32, DIMv / 32), 256, 0, stream>>>(pos_w1, pwt1_);
    pw_convert<<<dim3(PCK / 32, DIMv / 32), 256, 0, stream>>>(pos_w2, pwt2_);

    // time embedding + modulation vectors
    temb1_kernel<<<dim3(DIMv / 64, Bv), 256, 0, stream>>>(timev, t_w1, t_b1, hid_);
    temb2_kernel<<<dim3(DIMv / 64, Bv), 256, 0, stream>>>(hid_, t_w2, t_b2, st_);
    modvec_kernel<<<dim3(6 * DIMv / 64, Bv, DEPTHv), 256, 0, stream>>>(st_, adaln_w, adaln_b, mod_, 6 * DIMv);
    modvec_kernel<<<dim3(2 * DIMv / 64, Bv, 1), 256, 0, stream>>>(st_, fin_w, fin_b, fm_, 2 * DIMv);

    // input concat + projection
    concat_bf16<<<(unsigned)(((size_t)Bv * Tv * KCAT + 255) / 256), 256, 0, stream>>>(
        x, cond, table, text, catb_);
    gemm_bf16s<1><<<dim3(6, 64), 256, 0, stream>>>(
        catb_, wtinp_, inp_b, h_, nullptr, MT, DIMv, KCAT, DIMv, nullptr, 0, 0);

    // pos-conv block
    posconv_mfma<0, 0><<<dim3(Tv / 64, 16, Bv), 256, 0, stream>>>(h_, pwt1_, pos_b1, xnb2_);
    posconv_mfma<1, 1><<<dim3(Tv / 64, 16, Bv), 256, 0, stream>>>(xnb2_, pwt2_, pos_b2, h_);

    for (int l = 0; l < DEPTHv; l++) {
        const float* modl = mod_ + (size_t)l * Bv * 6 * DIMv;
        const float* cwl = conv_w + (size_t)l * CONVD * KCONVv;
        const float* cbl = conv_b + (size_t)l * CONVD;
        // ---- MSA/SSD branch ----
        ln_mod_kernel<1><<<MT, 256, 0, stream>>>(h_, xnb_, modl, DIMv, 0, 6 * DIMv);
        gemm_bf16<0><<<dim3(27, 32), 256, 0, stream>>>(
            xnb_, wtin_ + (size_t)l * 3456 * 768, nullptr, nullptr, zxb_,
            MT, DINP, DIMv, DINP, nullptr, 0, 0);
        ssd_front<<<dim3(25, CNv, Bv), 256, 0, stream>>>(
            zxb_, cwl, cbl, xT_, xbcBC_, CB_, BTg_);
        ssd_part1m<<<dim3(NHv, CNv, Bv), 256, 0, stream>>>(
            xT_, BTg_, zxb_, dt_bias + l * NHv, A_log + l * NHv, CB_, yb_, S_, ac_, at_);
        ssd_scan<<<(Bv * NHv * PHv * NSv + 255) / 256, 256, 0, stream>>>(S_, at_);
        ssd_part2m<<<dim3(NHv, CNv, Bv), 256, 0, stream>>>(
            xbcBC_, xT_, S_, ac_, Dp + l * NHv, yb_);
        gate_rms_kernel<<<MT, 256, 0, stream>>>(yb_, zxb_, rms_w + (size_t)l * DINNER, actb_);
        gemm_bf16s<3><<<dim3(6, 64), 256, 0, stream>>>(
            actb_, wtout_ + (size_t)l * 768 * 1536, nullptr, h_, nullptr,
            MT, DIMv, DINNER, DIMv, modl, 2 * DIMv, 6 * DIMv);
        // ---- MLP branch ----
        ln_mod_kernel<1><<<MT, 256, 0, stream>>>(h_, xnb_, modl, 4 * DIMv, 3 * DIMv, 6 * DIMv);
        gemm_bf16<2><<<dim3(12, 32), 256, 0, stream>>>(
            xnb_, wtff1_ + (size_t)l * 1536 * 768, ff_b1 + (size_t)l * FFIv, nullptr, actb_,
            MT, FFIv, DIMv, FFIv, nullptr, 0, 0);
        gemm_bf16s<4><<<dim3(6, 64), 256, 0, stream>>>(
            actb_, wtff2_ + (size_t)l * 768 * 1536, ff_b2 + (size_t)l * DIMv, h_, nullptr,
            MT, DIMv, FFIv, DIMv, modl, 5 * DIMv, 6 * DIMv);
    }

    // final modulated LN + projection
    ln_mod_kernel<1><<<MT, 256, 0, stream>>>(h_, xnb_, fm_, 0, DIMv, 2 * DIMv);
    gemm_bf16s<1><<<dim3(1, 64), 256, 0, stream>>>(
        xnb_, wtprj_, proj_b, (float*)d_out, nullptr, MT, MELv, DIMv, MELv, nullptr, 0, 0);
}

// Round 11
// 2556.637 us; speedup vs baseline: 1.0185x; 1.0185x over previous
//
#include <hip/hip_runtime.h>
#include <math.h>

// ---- problem constants ----
constexpr int Bv = 2, Tv = 2048, NTv = 512;
constexpr int DIMv = 768, DEPTHv = 8, MELv = 100, TDIMv = 512;
constexpr int DINNER = 1536, NSv = 128, PHv = 64, QQv = 64;
constexpr int NHv = DINNER / PHv;              // 24
constexpr int CONVD = DINNER + 2 * NSv;        // 1792
constexpr int DINP = 2 * DINNER + 2 * NSv + NHv; // 3352
constexpr int KCONVv = 4, FFIv = 2 * DIMv;     // 1536
constexpr int CNv = Tv / QQv;                  // 32
constexpr int PCK = 1504;                      // 31*48 padded
constexpr int KCAT = 768;                      // 712 padded to 64-mult

typedef unsigned short u16;
typedef unsigned int u32;
typedef __attribute__((ext_vector_type(8))) short short8v;
typedef __attribute__((ext_vector_type(4))) float f32x4;

__device__ __forceinline__ float siluf(float x) { return x / (1.f + expf(-x)); }
__device__ __forceinline__ float softplusf(float x) { return x > 20.f ? x : log1pf(expf(x)); }
__device__ __forceinline__ float mishf(float x) { return x * tanhf(softplusf(x)); }

__device__ __forceinline__ u16 f2bf(float v) {
    u32 u = __builtin_bit_cast(u32, v);
    u32 r = (u + 0x7fffu + ((u >> 16) & 1u)) >> 16;
    return (u16)r;
}
__device__ __forceinline__ float bf2f(u16 v) {
    u32 u = (u32)v << 16;
    return __builtin_bit_cast(float, u);
}
__device__ __forceinline__ float bf2fs(short v) { return bf2f((u16)v); }

__device__ __forceinline__ void gload16(const void* g, void* l) {
    __builtin_amdgcn_global_load_lds(
        (const __attribute__((address_space(1))) u32*)g,
        (__attribute__((address_space(3))) u32*)l, 16, 0, 0);
}

__device__ __forceinline__ float blockReduceSum(float v) {
    __shared__ float red[4];
    #pragma unroll
    for (int off = 32; off > 0; off >>= 1) v += __shfl_down(v, off, 64);
    __syncthreads();
    if ((threadIdx.x & 63) == 0) red[threadIdx.x >> 6] = v;
    __syncthreads();
    return red[0] + red[1] + red[2] + red[3];
}

// ================== GEMM epilogue (shared) ==================
template <int EPI>
__device__ __forceinline__ void gemm_epi(f32x4* acc, int row, int col,
        int N, int ldc, const float* bias, float* Cf, u16* Cb,
        const float* modv, int goff, int mstride) {
    if (col >= N) return;
    const float bv = (EPI == 1 || EPI == 2 || EPI == 4) ? bias[col] : 0.f;
    #pragma unroll
    for (int r = 0; r < 4; r++) {
        float v = (*acc)[r] + bv;
        if (EPI == 0) {
            Cb[(size_t)(row + r) * ldc + col] = f2bf(v);
        } else if (EPI == 2) {
            float xx = v;
            v = 0.5f * xx * (1.f + tanhf(0.7978845608028654f * (xx + 0.044715f * xx * xx * xx)));
            Cb[(size_t)(row + r) * ldc + col] = f2bf(v);
        } else if (EPI == 3 || EPI == 4) {
            const int bb = (row + r) >> 11;   // row / Tv
            float g = modv[(size_t)bb * mstride + goff + col];
            Cf[(size_t)(row + r) * ldc + col] += g * v;
        } else {
            Cf[(size_t)(row + r) * ldc + col] = v;
        }
    }
}

// ---- bf16 MFMA GEMM, BM=128/BN=128/BK=32, 2-phase dbuf, XCD-swizzled ----
template <int EPI>
__global__ __launch_bounds__(256) void gemm_bf16(const u16* __restrict__ A,
        const u16* __restrict__ BT, const float* __restrict__ bias,
        float* __restrict__ Cf, u16* __restrict__ Cb,
        int M, int N, int K, int ldc,
        const float* __restrict__ modv, int goff, int mstride) {
    __shared__ __align__(16) u16 As[2][128 * 32];
    __shared__ __align__(16) u16 Bs[2][128 * 32];
    const int tid = threadIdx.x;
    const int gx = gridDim.x;
    const int nwg = gx * gridDim.y;
    int flat = blockIdx.y * gx + blockIdx.x;
    const int qq = nwg >> 3;
    flat = (flat & 7) * qq + (flat >> 3);
    const int m0 = (flat / gx) * 128, n0 = (flat % gx) * 128;
    const int lane = tid & 63;
    const int wid = tid >> 6;
    const int wm = (wid >> 1) * 64, wn = (wid & 1) * 64;
    f32x4 acc[4][4] = {};
    const int srow = tid >> 2, sseg = (tid & 3) * 8;
    const u16* Ag = A + (size_t)(m0 + srow) * K + sseg;
    const u16* Bg = BT + (size_t)(n0 + srow) * K + sseg;
    const int lr = lane & 15, lk = (lane >> 4) * 8;
    gload16(Ag, &As[0][tid * 8]);
    gload16(Ag + (size_t)64 * K, &As[0][tid * 8 + 64 * 32]);
    gload16(Bg, &Bs[0][tid * 8]);
    gload16(Bg + (size_t)64 * K, &Bs[0][tid * 8 + 64 * 32]);
    __syncthreads();
    int cur = 0;
    for (int k0 = 0; k0 < K; k0 += 32) {
        if (k0 + 32 < K) {
            const int nb = cur ^ 1, kn = k0 + 32;
            gload16(Ag + kn, &As[nb][tid * 8]);
            gload16(Ag + kn + (size_t)64 * K, &As[nb][tid * 8 + 64 * 32]);
            gload16(Bg + kn, &Bs[nb][tid * 8]);
            gload16(Bg + kn + (size_t)64 * K, &Bs[nb][tid * 8 + 64 * 32]);
        }
        short8v a_f[4], b_f[4];
        #pragma unroll
        for (int i = 0; i < 4; i++)
            a_f[i] = *(const short8v*)&As[cur][(wm + i * 16 + lr) * 32 + lk];
        #pragma unroll
        for (int j = 0; j < 4; j++)
            b_f[j] = *(const short8v*)&Bs[cur][(wn + j * 16 + lr) * 32 + lk];
        #pragma unroll
        for (int i = 0; i < 4; i++)
            #pragma unroll
            for (int j = 0; j < 4; j++)
                acc[i][j] = __builtin_amdgcn_mfma_f32_16x16x32_bf16(a_f[i], b_f[j], acc[i][j], 0, 0, 0);
        __syncthreads();
        cur ^= 1;
    }
    const int r0 = (lane >> 4) * 4;
    #pragma unroll
    for (int i = 0; i < 4; i++)
        #pragma unroll
        for (int j = 0; j < 4; j++)
            gemm_epi<EPI>(&acc[i][j], m0 + wm + i * 16 + r0, n0 + wn + j * 16 + lr,
                          N, ldc, bias, Cf, Cb, modv, goff, mstride);
}

// ---- small bf16 GEMM: BM=64/BN=128/BK=32, 2-phase dbuf (24KB LDS), XCD-swizzled ----
template <int EPI>
__global__ __launch_bounds__(256) void gemm_bf16s(const u16* __restrict__ A,
        const u16* __restrict__ BT, const float* __restrict__ bias,
        float* __restrict__ Cf, u16* __restrict__ Cb,
        int M, int N, int K, int ldc,
        const float* __restrict__ modv, int goff, int mstride) {
    __shared__ __align__(16) u16 As[2][64 * 32];
    __shared__ __align__(16) u16 Bs[2][128 * 32];
    const int tid = threadIdx.x;
    const int gx = gridDim.x;
    const int nwg = gx * gridDim.y;
    int flat = blockIdx.y * gx + blockIdx.x;
    const int qq = nwg >> 3;
    flat = (flat & 7) * qq + (flat >> 3);
    const int m0 = (flat / gx) * 64, n0 = (flat % gx) * 128;
    const int lane = tid & 63;
    const int wid = tid >> 6;
    const int wn = wid * 32;
    f32x4 acc[4][2] = {};
    const int srow = tid >> 2, sseg = (tid & 3) * 8;
    const u16* Ag = A + (size_t)(m0 + srow) * K + sseg;
    const u16* Bg = BT + (size_t)(n0 + srow) * K + sseg;
    const int lr = lane & 15, lk = (lane >> 4) * 8;
    gload16(Ag, &As[0][tid * 8]);
    gload16(Bg, &Bs[0][tid * 8]);
    gload16(Bg + (size_t)64 * K, &Bs[0][tid * 8 + 64 * 32]);
    __syncthreads();
    int cur = 0;
    for (int k0 = 0; k0 < K; k0 += 32) {
        if (k0 + 32 < K) {
            const int nb = cur ^ 1, kn = k0 + 32;
            gload16(Ag + kn, &As[nb][tid * 8]);
            gload16(Bg + kn, &Bs[nb][tid * 8]);
            gload16(Bg + kn + (size_t)64 * K, &Bs[nb][tid * 8 + 64 * 32]);
        }
        short8v a_f[4], b_f[2];
        #pragma unroll
        for (int i = 0; i < 4; i++)
            a_f[i] = *(const short8v*)&As[cur][(i * 16 + lr) * 32 + lk];
        #pragma unroll
        for (int j = 0; j < 2; j++)
            b_f[j] = *(const short8v*)&Bs[cur][(wn + j * 16 + lr) * 32 + lk];
        #pragma unroll
        for (int i = 0; i < 4; i++)
            #pragma unroll
            for (int j = 0; j < 2; j++)
                acc[i][j] = __builtin_amdgcn_mfma_f32_16x16x32_bf16(a_f[i], b_f[j], acc[i][j], 0, 0, 0);
        __syncthreads();
        cur ^= 1;
    }
    const int r0 = (lane >> 4) * 4;
    #pragma unroll
    for (int i = 0; i < 4; i++)
        #pragma unroll
        for (int j = 0; j < 2; j++)
            gemm_epi<EPI>(&acc[i][j], m0 + i * 16 + r0, n0 + wn + j * 16 + lr,
                          N, ldc, bias, Cf, Cb, modv, goff, mstride);
}

// ---- batched weight convert: f32 [Kmax,N] (per layer) -> bf16 [Npad,Kd] ----
__global__ __launch_bounds__(256) void wt_convert_b(const float* __restrict__ W,
        u16* __restrict__ WT, int Kd, int N, int Kmax, int Npad) {
    const float* Wl = W + (size_t)blockIdx.z * Kmax * N;
    u16* WTl = WT + (size_t)blockIdx.z * Npad * Kd;
    __shared__ float t[32][33];
    const int n0 = blockIdx.x * 32, k0 = blockIdx.y * 32;
    const int c = threadIdx.x & 31, rq = (threadIdx.x >> 5) * 4;
    #pragma unroll
    for (int i = 0; i < 4; i++) {
        int n = n0 + c, k = k0 + rq + i;
        t[rq + i][c] = (n < N && k < Kmax) ? Wl[(size_t)k * N + n] : 0.f;
    }
    __syncthreads();
    #pragma unroll
    for (int i = 0; i < 4; i++)
        WTl[(size_t)(n0 + rq + i) * Kd + k0 + c] = f2bf(t[c][rq + i]);
}

// ---- pos-conv weight: w[31][48][768] -> WT[768][1504] bf16 ----
__global__ __launch_bounds__(256) void pw_convert(const float* __restrict__ w,
        u16* __restrict__ WT) {
    __shared__ float t[32][33];
    const int kk0 = blockIdx.x * 32, o0 = blockIdx.y * 32;
    const int c = threadIdx.x & 31, rq = (threadIdx.x >> 5) * 4;
    #pragma unroll
    for (int i = 0; i < 4; i++) {
        int kk = kk0 + rq + i;
        t[rq + i][c] = (kk < 1488) ? w[(size_t)kk * DIMv + o0 + c] : 0.f;
    }
    __syncthreads();
    #pragma unroll
    for (int i = 0; i < 4; i++)
        WT[(size_t)(o0 + rq + i) * PCK + kk0 + c] = f2bf(t[c][rq + i]);
}

// ---- grouped conv K=31 via implicit-im2col MFMA ----
template <int IN_BF, int FUSE>
__global__ __launch_bounds__(256) void posconv_mfma(const void* __restrict__ inv,
        const u16* __restrict__ WT, const float* __restrict__ bias,
        void* __restrict__ outv) {
    __shared__ __align__(16) u16 xs[95 * 48];
    const int t0 = blockIdx.x * 64, g = blockIdx.y, b = blockIdx.z;
    const int tid = threadIdx.x;
    for (int e = tid; e < 95 * 48; e += 256) {
        int rr = e / 48, cc = e % 48;
        int t = t0 - 15 + rr;
        float v = 0.f;
        if (t >= 0 && t < Tv) {
            size_t gi = ((size_t)b * Tv + t) * DIMv + g * 48 + cc;
            v = IN_BF ? bf2f(((const u16*)inv)[gi]) : ((const float*)inv)[gi];
        }
        xs[e] = f2bf(v);
    }
    __syncthreads();
    const int lane = tid & 63, w = tid >> 6;
    const int lr = lane & 15, lq8 = (lane >> 4) * 8, rq = (lane >> 4) * 4;
    const u16* arow = &xs[(w * 16 + lr) * 48 + lq8];
    const u16* brow = &WT[(size_t)(g * 48 + lr) * PCK + lq8];
    f32x4 acc[3] = {};
    #pragma unroll 2
    for (int ks = 0; ks < PCK / 32; ks++) {
        short8v a = *(const short8v*)(arow + ks * 32);
        #pragma unroll
        for (int j = 0; j < 3; j++) {
            short8v bf = *(const short8v*)(brow + (size_t)j * 16 * PCK + ks * 32);
            acc[j] = __builtin_amdgcn_mfma_f32_16x16x32_bf16(a, bf, acc[j], 0, 0, 0);
        }
    }
    #pragma unroll
    for (int j = 0; j < 3; j++) {
        const int o = g * 48 + j * 16 + lr;
        const float bvv = bias[o];
        #pragma unroll
        for (int r = 0; r < 4; r++) {
            const int t = t0 + w * 16 + rq + r;
            float v = acc[j][r] + bvv;
            size_t gi = ((size_t)b * Tv + t) * DIMv + o;
            if (FUSE == 0) ((u16*)outv)[gi] = f2bf(mishf(v));
            else ((float*)outv)[gi] += mishf(v);
        }
    }
}

// ---- time embedding stage 1 ----
__global__ __launch_bounds__(256) void temb1_kernel(const float* __restrict__ timev,
        const float* __restrict__ t_w1, const float* __restrict__ t_b1,
        float* __restrict__ hid) {
    const int b = blockIdx.y;
    const int o = blockIdx.x * 64 + (threadIdx.x & 63);
    const int ks = threadIdx.x >> 6;
    __shared__ float te[256];
    __shared__ float part[4][64];
    {
        int j = threadIdx.x, f = j & 127;
        float fr = expf(-logf(10000.f) / 127.f * (float)f);
        float ang = 1000.f * timev[b] * fr;
        te[j] = (j < 128) ? sinf(ang) : cosf(ang);
    }
    __syncthreads();
    float acc = 0.f;
    #pragma unroll 8
    for (int k = ks * 64; k < ks * 64 + 64; k++) acc += te[k] * t_w1[(size_t)k * DIMv + o];
    part[ks][threadIdx.x & 63] = acc;
    __syncthreads();
    if (threadIdx.x < 64) {
        float r = part[0][threadIdx.x] + part[1][threadIdx.x] + part[2][threadIdx.x] + part[3][threadIdx.x]
                + t_b1[o];
        hid[b * DIMv + o] = siluf(r);
    }
}

// ---- time embedding stage 2 ----
__global__ __launch_bounds__(256) void temb2_kernel(const float* __restrict__ hid,
        const float* __restrict__ t_w2, const float* __restrict__ t_b2,
        float* __restrict__ st_out) {
    const int b = blockIdx.y;
    const int o = blockIdx.x * 64 + (threadIdx.x & 63);
    const int ks = threadIdx.x >> 6;
    __shared__ float hv[DIMv];
    __shared__ float part[4][64];
    for (int j = threadIdx.x; j < DIMv; j += 256) hv[j] = hid[b * DIMv + j];
    __syncthreads();
    float acc = 0.f;
    #pragma unroll 8
    for (int k = ks * 192; k < ks * 192 + 192; k++) acc += hv[k] * t_w2[(size_t)k * DIMv + o];
    part[ks][threadIdx.x & 63] = acc;
    __syncthreads();
    if (threadIdx.x < 64) {
        float r = part[0][threadIdx.x] + part[1][threadIdx.x] + part[2][threadIdx.x] + part[3][threadIdx.x]
                + t_b2[o];
        st_out[b * DIMv + o] = siluf(r);
    }
}

// ---- batched modulation vectors ----
__global__ __launch_bounds__(256) void modvec_kernel(const float* __restrict__ st,
        const float* __restrict__ W, const float* __restrict__ bias,
        float* __restrict__ out, int N) {
    const int l = blockIdx.z, b = blockIdx.y;
    const int o = blockIdx.x * 64 + (threadIdx.x & 63);
    const int ks = threadIdx.x >> 6;
    __shared__ float sv[DIMv];
    __shared__ float part[4][64];
    for (int j = threadIdx.x; j < DIMv; j += 256) sv[j] = st[b * DIMv + j];
    __syncthreads();
    const float* Wl = W + (size_t)l * DIMv * N + o;
    float acc = 0.f;
    #pragma unroll 8
    for (int k = ks * 192; k < ks * 192 + 192; k++) acc += sv[k] * Wl[(size_t)k * N];
    part[ks][threadIdx.x & 63] = acc;
    __syncthreads();
    if (threadIdx.x < 64) {
        float r = part[0][threadIdx.x] + part[1][threadIdx.x] + part[2][threadIdx.x] + part[3][threadIdx.x]
                + bias[(size_t)l * N + o];
        out[((size_t)l * Bv + b) * N + o] = r;
    }
}

// ---- concat [x, cond, temb] -> bf16, K-padded to 768 ----
__global__ void concat_bf16(const float* __restrict__ x, const float* __restrict__ cond,
                            const float* __restrict__ table, const int* __restrict__ text,
                            u16* __restrict__ cat) {
    size_t i = (size_t)blockIdx.x * 256 + threadIdx.x;
    const size_t total = (size_t)Bv * Tv * KCAT;
    if (i >= total) return;
    int j = (int)(i % KCAT);
    size_t row = i / KCAT;
    int t = (int)(row % Tv), b = (int)(row / Tv);
    float v = 0.f;
    if (j < MELv) v = x[row * MELv + j];
    else if (j < 2 * MELv) v = cond[row * MELv + (j - MELv)];
    else if (j < 712) {
        int idx = (t < NTv) ? (text[b * NTv + t] + 1) : 0;
        v = table[(size_t)idx * TDIMv + (j - 2 * MELv)];
    }
    cat[i] = f2bf(v);
}

// ---- LayerNorm with adaLN modulation; BF=1 writes bf16 ----
template <int BF>
__global__ __launch_bounds__(256) void ln_mod_kernel(const float* __restrict__ h,
        void* __restrict__ outv, const float* __restrict__ modv,
        int sc_off, int sh_off, int mod_stride) {
    const int row = blockIdx.x;
    const int b = row / Tv;
    const float* hr = h + (size_t)row * DIMv;
    float s = 0.f;
    for (int j = threadIdx.x; j < DIMv; j += 256) s += hr[j];
    s = blockReduceSum(s);
    const float m = s / DIMv;
    float v = 0.f;
    for (int j = threadIdx.x; j < DIMv; j += 256) { float d = hr[j] - m; v += d * d; }
    v = blockReduceSum(v);
    const float rstd = rsqrtf(v / DIMv + 1e-6f);
    const float* mb = modv + (size_t)b * mod_stride;
    for (int j = threadIdx.x; j < DIMv; j += 256) {
        float val = (hr[j] - m) * rstd * (1.f + mb[sc_off + j]) + mb[sh_off + j];
        if (BF) ((u16*)outv)[(size_t)row * DIMv + j] = f2bf(val);
        else ((float*)outv)[(size_t)row * DIMv + j] = val;
    }
}

// ---- dwconv for x channels, writing TRANSPOSED xT[bc][p][s] (bf16), 9.7KB LDS ----
__global__ __launch_bounds__(256) void dwconvT(const u16* __restrict__ zxb,
        const float* __restrict__ cw, const float* __restrict__ cb,
        u16* __restrict__ xT) {
    __shared__ __align__(16) u16 in_s[67 * 72];   // [s'][p], s' <-> t = c*64 + s' - 3
    const int pb = blockIdx.x;        // 0..23 (64 channels each)
    const int c = blockIdx.y, b = blockIdx.z;
    const int bc = b * CNv + c;
    const int tid = threadIdx.x;
    for (int e = tid; e < 67 * 8; e += 256) {
        int sp = e >> 3, p8 = (e & 7) * 8;
        int t = c * 64 + sp - 3;
        short8v v = {};
        if (t >= 0)
            v = *(const short8v*)&zxb[((size_t)b * Tv + t) * DINP + DINNER + pb * 64 + p8];
        *(short8v*)&in_s[sp * 72 + p8] = v;
    }
    __syncthreads();
    const int p = tid >> 2, sb = (tid & 3) * 16;
    const int ch = pb * 64 + p;
    const float w0 = cw[ch * 4], w1 = cw[ch * 4 + 1], w2 = cw[ch * 4 + 2], w3 = cw[ch * 4 + 3];
    const float bb = cb[ch];
    short8v o0, o1;
    #pragma unroll
    for (int i = 0; i < 16; i++) {
        int s = sb + i;
        float acc = bb + bf2f(in_s[s * 72 + p]) * w0 + bf2f(in_s[(s + 1) * 72 + p]) * w1
                  + bf2f(in_s[(s + 2) * 72 + p]) * w2 + bf2f(in_s[(s + 3) * 72 + p]) * w3;
        short r = (short)f2bf(siluf(acc));
        if (i < 8) o0[i] = r; else o1[i - 8] = r;
    }
    u16* dst = xT + ((size_t)bc * DINNER + ch) * 64 + sb;
    *(short8v*)dst = o0;
    *(short8v*)(dst + 8) = o1;
}

// ---- SSD: fused B/C dwconv + CB = C.B^T (f32) + BTg[n][s] (bf16), per (b,c) ----
__global__ __launch_bounds__(256) void ssd_cb(const u16* __restrict__ zxb,
        const float* __restrict__ cw, const float* __restrict__ cbv,
        u16* __restrict__ xbcBC, float* __restrict__ CBg, u16* __restrict__ BTg) {
    constexpr int ST = 136;
    __shared__ __align__(16) u16 Cs[64 * ST];
    __shared__ __align__(16) u16 Bs[64 * ST];
    const int c = blockIdx.x, b = blockIdx.y;
    const int bc = b * CNv + c;
    const int tid = threadIdx.x;
    const size_t rowbase = (size_t)b * Tv + (size_t)c * QQv;
    // fused causal dwconv(K=4)+silu for the 256 B/C channels
    for (int e = tid; e < 64 * 32; e += 256) {
        int r = e >> 5, n8 = (e & 31) * 8;
        size_t row = rowbase + r;
        int t = c * 64 + r;
        const u16* base = zxb + row * DINP + DINNER + n8;
        float acc[8];
        #pragma unroll
        for (int u = 0; u < 8; u++) acc[u] = cbv[DINNER + n8 + u];
        #pragma unroll
        for (int k = 0; k < KCONVv; k++) {
            const int d = k - 3;
            if (t + d < 0) continue;
            short8v tv = *(const short8v*)(base + (ptrdiff_t)d * DINP);
            #pragma unroll
            for (int u = 0; u < 8; u++)
                acc[u] += bf2fs(tv[u]) * cw[(DINNER + n8 + u) * KCONVv + k];
        }
        short8v o;
        #pragma unroll
        for (int u = 0; u < 8; u++) o[u] = (short)f2bf(siluf(acc[u]));
        if (n8 < NSv) *(short8v*)&Bs[r * ST + n8] = o;
        else *(short8v*)&Cs[r * ST + (n8 - NSv)] = o;
        *(short8v*)&xbcBC[row * 256 + n8] = o;
    }
    __syncthreads();
    // transposed B to global (shared by all 24 heads in part1)
    u16* btg = BTg + (size_t)bc * (NSv * QQv);
    for (int e = tid; e < 128 * 64; e += 256) {
        int n = e >> 6, s = e & 63;
        btg[e] = Bs[s * ST + n];
    }
    const int lane = tid & 63, w = tid >> 6;
    const int lr = lane & 15, lk8 = (lane >> 4) * 8, rq = (lane >> 4) * 4;
    f32x4 acc[4] = {};
    #pragma unroll
    for (int ks = 0; ks < 4; ks++) {
        short8v a = *(const short8v*)&Cs[(w * 16 + lr) * ST + ks * 32 + lk8];
        #pragma unroll
        for (int j = 0; j < 4; j++) {
            short8v bf = *(const short8v*)&Bs[(j * 16 + lr) * ST + ks * 32 + lk8];
            acc[j] = __builtin_amdgcn_mfma_f32_16x16x32_bf16(a, bf, acc[j], 0, 0, 0);
        }
    }
    float* out = CBg + (size_t)bc * 4096;
    #pragma unroll
    for (int j = 0; j < 4; j++)
        #pragma unroll
        for (int r = 0; r < 4; r++)
            out[(w * 16 + rq + r) * 64 + j * 16 + lr] = acc[j][r];
}

// ---- SSD part1: scan; y_in = Wsm' @ xT^T; S = (xT.dtrev) @ B  (S bf16) ----
__global__ __launch_bounds__(256) void ssd_part1m(const u16* __restrict__ xT,
        const u16* __restrict__ BTg, const u16* __restrict__ zxb,
        const float* __restrict__ dt_bias, const float* __restrict__ A_log,
        const float* __restrict__ CBg, u16* __restrict__ ybuf,
        u16* __restrict__ Sg, float* __restrict__ acg, float* __restrict__ atg) {
    constexpr int ST64 = 72;
    __shared__ __align__(16) u16 xTs[64 * ST64];   // [p][s]
    __shared__ __align__(16) u16 Wsm[64 * ST64];   // [q][s]  (cb*exp*dt)
    __shared__ __align__(16) u16 BTs[128 * ST64];  // [n][s]  (B^T * dt*erev)
    __shared__ float ac[64], dts[64], dtrev[64];
    const int h = blockIdx.x, c = blockIdx.y, b = blockIdx.z;
    const int bc = b * CNv + c;
    const int tid = threadIdx.x;
    const size_t rowbase = (size_t)b * Tv + (size_t)c * QQv;
    const size_t bch = ((size_t)bc) * NHv + h;
    if (tid < 64) {
        float raw = bf2f(zxb[(rowbase + tid) * DINP + DINNER + CONVD + h]) + dt_bias[h];
        float dtv = softplusf(raw);
        dts[tid] = dtv;
        float v = dtv * (-expf(A_log[h]));
        #pragma unroll
        for (int off = 1; off < 64; off <<= 1) {
            float t = __shfl_up(v, off, 64);
            if (tid >= off) v += t;
        }
        ac[tid] = v;
        float v63 = __shfl(v, 63, 64);
        dtrev[tid] = dtv * expf(v63 - v);
        acg[bch * 64 + tid] = v;
        if (tid == 63) atg[bch] = expf(v63);
    }
    {
        const u16* src = xT + ((size_t)bc * DINNER + h * PHv) * 64;
        for (int e = tid; e < 64 * 8; e += 256) {
            int p = e >> 3, s8 = (e & 7) * 8;
            *(short8v*)&xTs[p * ST64 + s8] = *(const short8v*)(src + p * 64 + s8);
        }
    }
    __syncthreads();
    {
        const u16* btg = BTg + (size_t)bc * (NSv * QQv);
        for (int e = tid; e < 128 * 8; e += 256) {
            int n = e >> 3, s8 = (e & 7) * 8;
            short8v v = *(const short8v*)(btg + n * 64 + s8);
            short8v o;
            #pragma unroll
            for (int u = 0; u < 8; u++)
                o[u] = (short)f2bf(bf2fs(v[u]) * dtrev[s8 + u]);
            *(short8v*)&BTs[n * ST64 + s8] = o;
        }
        const float* cbrow = CBg + (size_t)bc * 4096;
        for (int e = tid; e < 1024; e += 256) {
            int q = e >> 4, s4 = (e & 15) * 4;
            f32x4 cb4 = *(const f32x4*)&cbrow[q * 64 + s4];
            float aq = ac[q];
            #pragma unroll
            for (int u = 0; u < 4; u++) {
                int s = s4 + u;
                float wv = (s <= q) ? cb4[u] * expf(aq - ac[s]) * dts[s] : 0.f;
                Wsm[q * ST64 + s] = f2bf(wv);
            }
        }
    }
    __syncthreads();
    const int lane = tid & 63, w = tid >> 6;
    const int lr = lane & 15, lk8 = (lane >> 4) * 8, rq = (lane >> 4) * 4;
    // y_in[q][p]
    {
        f32x4 acc[4] = {};
        #pragma unroll
        for (int ks = 0; ks < 2; ks++) {
            short8v bf = *(const short8v*)&xTs[(w * 16 + lr) * ST64 + ks * 32 + lk8];
            #pragma unroll
            for (int i = 0; i < 4; i++) {
                short8v a = *(const short8v*)&Wsm[(i * 16 + lr) * ST64 + ks * 32 + lk8];
                acc[i] = __builtin_amdgcn_mfma_f32_16x16x32_bf16(a, bf, acc[i], 0, 0, 0);
            }
        }
        #pragma unroll
        for (int i = 0; i < 4; i++)
            #pragma unroll
            for (int r = 0; r < 4; r++) {
                int q = i * 16 + rq + r, p = w * 16 + lr;
                ybuf[(rowbase + q) * DINNER + h * PHv + p] = f2bf(acc[i][r]);
            }
    }
    // S[p][n]
    {
        f32x4 acc[4][2] = {};
        #pragma unroll
        for (int ks = 0; ks < 2; ks++) {
            short8v a[4];
            #pragma unroll
            for (int i = 0; i < 4; i++)
                a[i] = *(const short8v*)&xTs[(i * 16 + lr) * ST64 + ks * 32 + lk8];
            #pragma unroll
            for (int j = 0; j < 2; j++) {
                short8v bf = *(const short8v*)&BTs[(w * 32 + j * 16 + lr) * ST64 + ks * 32 + lk8];
                #pragma unroll
                for (int i = 0; i < 4; i++)
                    acc[i][j] = __builtin_amdgcn_mfma_f32_16x16x32_bf16(a[i], bf, acc[i][j], 0, 0, 0);
            }
        }
        u16* So = Sg + bch * (PHv * NSv);
        #pragma unroll
        for (int i = 0; i < 4; i++)
            #pragma unroll
            for (int j = 0; j < 2; j++)
                #pragma unroll
                for (int r = 0; r < 4; r++)
                    So[(i * 16 + rq + r) * NSv + w * 32 + j * 16 + lr] = f2bf(acc[i][j][r]);
    }
}

// ---- inter-chunk scan (bf16 storage, f32 accumulator) ----
__global__ void ssd_scan(u16* __restrict__ Sg, const float* __restrict__ atg) {
    int idx = blockIdx.x * 256 + threadIdx.x;
    if (idx >= Bv * NHv * PHv * NSv) return;
    int n = idx % NSv;
    int p = (idx / NSv) % PHv;
    int h = (idx / (NSv * PHv)) % NHv;
    int b = idx / (NSv * PHv * NHv);
    float H = 0.f;
    for (int c = 0; c < CNv; c++) {
        size_t bch = ((size_t)b * CNv + c) * NHv + h;
        size_t off = bch * PHv * NSv + (size_t)p * NSv + n;
        float s = bf2f(Sg[off]);
        float at = atg[bch];
        Sg[off] = f2bf(H);
        H = at * H + s;
    }
}

// ---- SSD part2: y += (C @ prev^T)*eac + D*x ----
__global__ __launch_bounds__(256) void ssd_part2m(const u16* __restrict__ xbcBC,
        const u16* __restrict__ xT, const u16* __restrict__ Sg,
        const float* __restrict__ acg, const float* __restrict__ Dp,
        u16* __restrict__ ybuf) {
    constexpr int ST = 136;
    __shared__ __align__(16) u16 Cs[64 * ST];
    __shared__ __align__(16) u16 Ps[64 * ST];
    __shared__ float eac[64];
    const int h = blockIdx.x, c = blockIdx.y, b = blockIdx.z;
    const int bc = b * CNv + c;
    const int tid = threadIdx.x;
    const size_t rowbase = (size_t)b * Tv + (size_t)c * QQv;
    const size_t bch = ((size_t)bc) * NHv + h;
    if (tid < 64) eac[tid] = expf(acg[bch * 64 + tid]);
    for (int e = tid; e < 64 * 16; e += 256) {
        int r = e >> 4, n8 = (e & 15) * 8;
        *(short8v*)&Cs[r * ST + n8] =
            *(const short8v*)&xbcBC[(rowbase + r) * 256 + NSv + n8];
        *(short8v*)&Ps[r * ST + n8] =
            *(const short8v*)&Sg[bch * (PHv * NSv) + (size_t)r * NSv + n8];
    }
    __syncthreads();
    const int lane = tid & 63, w = tid >> 6;
    const int lr = lane & 15, lk8 = (lane >> 4) * 8, rq = (lane >> 4) * 4;
    f32x4 acc[4] = {};
    #pragma unroll
    for (int ks = 0; ks < 4; ks++) {
        short8v bf = *(const short8v*)&Ps[(w * 16 + lr) * ST + ks * 32 + lk8];
        #pragma unroll
        for (int i = 0; i < 4; i++) {
            short8v a = *(const short8v*)&Cs[(i * 16 + lr) * ST + ks * 32 + lk8];
            acc[i] = __builtin_amdgcn_mfma_f32_16x16x32_bf16(a, bf, acc[i], 0, 0, 0);
        }
    }
    const float Dh = Dp[h];
    const int p = w * 16 + lr;
    const u16* xrow = xT + ((size_t)bc * DINNER + h * PHv + p) * 64;
    #pragma unroll
    for (int i = 0; i < 4; i++)
        #pragma unroll
        for (int r = 0; r < 4; r++) {
            int q = i * 16 + rq + r;
            size_t yi = (rowbase + q) * DINNER + h * PHv + p;
            float xv = bf2f(xrow[q]);
            ybuf[yi] = f2bf(bf2f(ybuf[yi]) + acc[i][r] * eac[q] + Dh * xv);
        }
}

// ---- gate by silu(z), RMS norm, * rms_w (bf16 in/out) ----
__global__ __launch_bounds__(256) void gate_rms_kernel(const u16* __restrict__ y,
        const u16* __restrict__ zxb, const float* __restrict__ rms_w,
        u16* __restrict__ yb) {
    const int row = blockIdx.x;
    const u16* yr = y + (size_t)row * DINNER;
    const u16* zr = zxb + (size_t)row * DINP;
    float vals[8];
    float ss = 0.f;
    const int tid = threadIdx.x;
    if (tid < 192) {
        short8v yv = *(const short8v*)(yr + tid * 8);
        short8v zv = *(const short8v*)(zr + tid * 8);
        #pragma unroll
        for (int u = 0; u < 8; u++) {
            float v = bf2fs(yv[u]) * siluf(bf2fs(zv[u]));
            vals[u] = v;
            ss += v * v;
        }
    }
    ss = blockReduceSum(ss);
    const float scale = rsqrtf(ss / DINNER + 1e-5f);
    if (tid < 192) {
        short8v outv;
        #pragma unroll
        for (int u = 0; u < 8; u++)
            outv[u] = (short)f2bf(vals[u] * scale * rms_w[tid * 8 + u]);
        *(short8v*)(yb + (size_t)row * DINNER + tid * 8) = outv;
    }
}

extern "C" void kernel_launch(void* const* d_in, const int* in_sizes, int n_in,
                              void* d_out, int out_size, void* d_ws, size_t ws_size,
                              hipStream_t stream) {
    int s3 = (in_sizes[3] == Bv * NTv) ? 1 : 0;
    const float* x      = (const float*)d_in[0];
    const float* cond   = (const float*)d_in[1];
    const float* timev  = (const float*)d_in[2];
    const int*   text   = (const int*)(s3 ? d_in[3] : d_in[32]);
    const float* table  = (const float*)d_in[3 + s3];
    const float* inp_w  = (const float*)d_in[4 + s3];
    const float* inp_b  = (const float*)d_in[5 + s3];
    const float* pos_w1 = (const float*)d_in[6 + s3];
    const float* pos_b1 = (const float*)d_in[7 + s3];
    const float* pos_w2 = (const float*)d_in[8 + s3];
    const float* pos_b2 = (const float*)d_in[9 + s3];
    const float* t_w1   = (const float*)d_in[10 + s3];
    const float* t_b1   = (const float*)d_in[11 + s3];
    const float* t_w2   = (const float*)d_in[12 + s3];
    const float* t_b2   = (const float*)d_in[13 + s3];
    const float* adaln_w= (const float*)d_in[14 + s3];
    const float* adaln_b= (const float*)d_in[15 + s3];
    const float* in_w   = (const float*)d_in[16 + s3];
    const float* conv_w = (const float*)d_in[17 + s3];
    const float* conv_b = (const float*)d_in[18 + s3];
    const float* dt_bias= (const float*)d_in[19 + s3];
    const float* A_log  = (const float*)d_in[20 + s3];
    const float* Dp     = (const float*)d_in[21 + s3];
    const float* rms_w  = (const float*)d_in[22 + s3];
    const float* out_w  = (const float*)d_in[23 + s3];
    const float* ff_w1  = (const float*)d_in[24 + s3];
    const float* ff_b1  = (const float*)d_in[25 + s3];
    const float* ff_w2  = (const float*)d_in[26 + s3];
    const float* ff_b2  = (const float*)d_in[27 + s3];
    const float* fin_w  = (const float*)d_in[28 + s3];
    const float* fin_b  = (const float*)d_in[29 + s3];
    const float* proj_w = (const float*)d_in[30 + s3];
    const float* proj_b = (const float*)d_in[31 + s3];

    // ---- workspace layout ----
    float* ws = (float*)d_ws;
    const size_t n_h = (size_t)Bv * Tv * DIMv;
    size_t off = 0;
    auto nx = [&](size_t n) { float* p = ws + off; off += n; return p; };
    float* h_   = nx(n_h);
    float* ac_  = nx((size_t)Bv * CNv * NHv * QQv);
    float* at_  = nx((size_t)Bv * CNv * NHv);
    float* CB_  = nx((size_t)Bv * CNv * QQv * QQv);
    float* st_  = nx((size_t)Bv * DIMv);
    float* hid_ = nx((size_t)Bv * DIMv);
    float* mod_ = nx((size_t)DEPTHv * Bv * 6 * DIMv);
    float* fm_  = nx((size_t)Bv * 2 * DIMv);
    off = (off + 15) & ~(size_t)15;
    u16* wtin_  = (u16*)(ws + off);
    u16* wtout_ = wtin_  + (size_t)DEPTHv * 3456 * 768;
    u16* wtff1_ = wtout_ + (size_t)DEPTHv * 768 * 1536;
    u16* wtff2_ = wtff1_ + (size_t)DEPTHv * 1536 * 768;
    u16* wtinp_ = wtff2_ + (size_t)DEPTHv * 768 * 1536;
    u16* wtprj_ = wtinp_ + (size_t)768 * KCAT;
    u16* pwt1_  = wtprj_ + (size_t)128 * 768;
    u16* pwt2_  = pwt1_  + (size_t)768 * PCK;
    u16* zxb_   = pwt2_  + (size_t)768 * PCK;     // 4096x3352
    u16* xbcBC_ = zxb_   + (size_t)4096 * DINP;   // 4096x256
    u16* xT_    = xbcBC_ + (size_t)4096 * 256;    // 64 x 1536 x 64
    u16* BTg_   = xT_    + (size_t)64 * DINNER * 64;  // 64 x 128 x 64
    u16* S_     = BTg_   + (size_t)64 * NSv * 64; // bf16 state
    u16* yb_    = S_     + (size_t)Bv * CNv * NHv * PHv * NSv;
    u16* xnb_   = yb_    + (size_t)4096 * 1536;   // 4096x768
    u16* actb_  = xnb_   + (size_t)4096 * 768;    // 4096x1536
    u16* xnb2_  = actb_  + (size_t)4096 * 1536;   // 4096x768
    u16* catb_  = xnb2_  + (size_t)4096 * 768;    // 4096x768

    const int MT = Bv * Tv;

    // ---- batched weight conversions (all layers upfront) ----
    wt_convert_b<<<dim3(3456 / 32, 768 / 32, DEPTHv), 256, 0, stream>>>(
        in_w, wtin_, 768, DINP, DIMv, 3456);
    wt_convert_b<<<dim3(768 / 32, 1536 / 32, DEPTHv), 256, 0, stream>>>(
        out_w, wtout_, 1536, DIMv, DINNER, 768);
    wt_convert_b<<<dim3(1536 / 32, 768 / 32, DEPTHv), 256, 0, stream>>>(
        ff_w1, wtff1_, 768, FFIv, DIMv, 1536);
    wt_convert_b<<<dim3(768 / 32, 1536 / 32, DEPTHv), 256, 0, stream>>>(
        ff_w2, wtff2_, 1536, DIMv, FFIv, 768);
    wt_convert_b<<<dim3(768 / 32, KCAT / 32, 1), 256, 0, stream>>>(
        inp_w, wtinp_, KCAT, DIMv, 712, 768);
    wt_convert_b<<<dim3(128 / 32, 768 / 32, 1), 256, 0, stream>>>(
        proj_w, wtprj_, 768, MELv, DIMv, 128);
    pw_convert<<<dim3(PCK / 32, DIMv / 32), 256, 0, stream>>>(pos_w1, pwt1_);
    pw_convert<<<dim3(PCK / 32, DIMv / 32), 256, 0, stream>>>(pos_w2, pwt2_);

    // time embedding + modulation vectors
    temb1_kernel<<<dim3(DIMv / 64, Bv), 256, 0, stream>>>(timev, t_w1, t_b1, hid_);
    temb2_kernel<<<dim3(DIMv / 64, Bv), 256, 0, stream>>>(hid_, t_w2, t_b2, st_);
    modvec_kernel<<<dim3(6 * DIMv / 64, Bv, DEPTHv), 256, 0, stream>>>(st_, adaln_w, adaln_b, mod_, 6 * DIMv);
    modvec_kernel<<<dim3(2 * DIMv / 64, Bv, 1), 256, 0, stream>>>(st_, fin_w, fin_b, fm_, 2 * DIMv);

    // input concat + projection
    concat_bf16<<<(unsigned)(((size_t)Bv * Tv * KCAT + 255) / 256), 256, 0, stream>>>(
        x, cond, table, text, catb_);
    gemm_bf16s<1><<<dim3(6, 64), 256, 0, stream>>>(
        catb_, wtinp_, inp_b, h_, nullptr, MT, DIMv, KCAT, DIMv, nullptr, 0, 0);

    // pos-conv block
    posconv_mfma<0, 0><<<dim3(Tv / 64, 16, Bv), 256, 0, stream>>>(h_, pwt1_, pos_b1, xnb2_);
    posconv_mfma<1, 1><<<dim3(Tv / 64, 16, Bv), 256, 0, stream>>>(xnb2_, pwt2_, pos_b2, h_);

    for (int l = 0; l < DEPTHv; l++) {
        const float* modl = mod_ + (size_t)l * Bv * 6 * DIMv;
        const float* cwl = conv_w + (size_t)l * CONVD * KCONVv;
        const float* cbl = conv_b + (size_t)l * CONVD;
        // ---- MSA/SSD branch ----
        ln_mod_kernel<1><<<MT, 256, 0, stream>>>(h_, xnb_, modl, DIMv, 0, 6 * DIMv);
        gemm_bf16<0><<<dim3(27, 32), 256, 0, stream>>>(
            xnb_, wtin_ + (size_t)l * 3456 * 768, nullptr, nullptr, zxb_,
            MT, DINP, DIMv, DINP, nullptr, 0, 0);
        dwconvT<<<dim3(DINNER / 64, CNv, Bv), 256, 0, stream>>>(zxb_, cwl, cbl, xT_);
        ssd_cb<<<dim3(CNv, Bv), 256, 0, stream>>>(zxb_, cwl, cbl, xbcBC_, CB_, BTg_);
        ssd_part1m<<<dim3(NHv, CNv, Bv), 256, 0, stream>>>(
            xT_, BTg_, zxb_, dt_bias + l * NHv, A_log + l * NHv, CB_, yb_, S_, ac_, at_);
        ssd_scan<<<(Bv * NHv * PHv * NSv + 255) / 256, 256, 0, stream>>>(S_, at_);
        ssd_part2m<<<dim3(NHv, CNv, Bv), 256, 0, stream>>>(
            xbcBC_, xT_, S_, ac_, Dp + l * NHv, yb_);
        gate_rms_kernel<<<MT, 256, 0, stream>>>(yb_, zxb_, rms_w + (size_t)l * DINNER, actb_);
        gemm_bf16s<3><<<dim3(6, 64), 256, 0, stream>>>(
            actb_, wtout_ + (size_t)l * 768 * 1536, nullptr, h_, nullptr,
            MT, DIMv, DINNER, DIMv, modl, 2 * DIMv, 6 * DIMv);
        // ---- MLP branch ----
        ln_mod_kernel<1><<<MT, 256, 0, stream>>>(h_, xnb_, modl, 4 * DIMv, 3 * DIMv, 6 * DIMv);
        gemm_bf16<2><<<dim3(12, 32), 256, 0, stream>>>(
            xnb_, wtff1_ + (size_t)l * 1536 * 768, ff_b1 + (size_t)l * FFIv, nullptr, actb_,
            MT, FFIv, DIMv, FFIv, nullptr, 0, 0);
        gemm_bf16s<4><<<dim3(6, 64), 256, 0, stream>>>(
            actb_, wtff2_ + (size_t)l * 768 * 1536, ff_b2 + (size_t)l * DIMv, h_, nullptr,
            MT, DIMv, FFIv, DIMv, modl, 5 * DIMv, 6 * DIMv);
    }

    // final modulated LN + projection
    ln_mod_kernel<1><<<MT, 256, 0, stream>>>(h_, xnb_, fm_, 0, DIMv, 2 * DIMv);
    gemm_bf16s<1><<<dim3(1, 64), 256, 0, stream>>>(
        xnb_, wtprj_, proj_b, (float*)d_out, nullptr, MT, MELv, DIMv, MELv, nullptr, 0, 0);
}

// Round 12
// 2478.079 us; speedup vs baseline: 1.0508x; 1.0317x over previous
//
#include <hip/hip_runtime.h>
#include <math.h>

// ---- problem constants ----
constexpr int Bv = 2, Tv = 2048, NTv = 512;
constexpr int DIMv = 768, DEPTHv = 8, MELv = 100, TDIMv = 512;
constexpr int DINNER = 1536, NSv = 128, PHv = 64, QQv = 64;
constexpr int NHv = DINNER / PHv;              // 24
constexpr int CONVD = DINNER + 2 * NSv;        // 1792
constexpr int DINP = 2 * DINNER + 2 * NSv + NHv; // 3352
constexpr int KCONVv = 4, FFIv = 2 * DIMv;     // 1536
constexpr int CNv = Tv / QQv;                  // 32
constexpr int PCK = 1504;                      // 31*48 padded
constexpr int KCAT = 736;                      // 712 padded

typedef unsigned short u16;
typedef unsigned int u32;
typedef __attribute__((ext_vector_type(8))) short short8v;
typedef __attribute__((ext_vector_type(4))) float f32x4;

__device__ __forceinline__ float siluf(float x) { return x / (1.f + expf(-x)); }
__device__ __forceinline__ float softplusf(float x) { return x > 20.f ? x : log1pf(expf(x)); }
__device__ __forceinline__ float mishf(float x) { return x * tanhf(softplusf(x)); }

__device__ __forceinline__ u16 f2bf(float v) {
    u32 u = __builtin_bit_cast(u32, v);
    u32 r = (u + 0x7fffu + ((u >> 16) & 1u)) >> 16;
    return (u16)r;
}
__device__ __forceinline__ float bf2f(u16 v) {
    u32 u = (u32)v << 16;
    return __builtin_bit_cast(float, u);
}
__device__ __forceinline__ float bf2fs(short v) { return bf2f((u16)v); }

__device__ __forceinline__ void gload16(const void* g, void* l) {
    __builtin_amdgcn_global_load_lds(
        (const __attribute__((address_space(1))) u32*)g,
        (__attribute__((address_space(3))) u32*)l, 16, 0, 0);
}

__device__ __forceinline__ float blockReduceSum(float v) {
    __shared__ float red[4];
    #pragma unroll
    for (int off = 32; off > 0; off >>= 1) v += __shfl_down(v, off, 64);
    __syncthreads();
    if ((threadIdx.x & 63) == 0) red[threadIdx.x >> 6] = v;
    __syncthreads();
    return red[0] + red[1] + red[2] + red[3];
}

// ---- bf16 MFMA GEMM, 2-phase double-buffered, XCD-swizzled ----
// BIG=1: BM=128 ; BIG=0: BM=64.  Requires grid count % 8 == 0.
// EPI: 0 bf16 out, 1 +bias f32, 2 +bias gelu bf16, 3 h+=g*acc, 4 h+=g*(acc+bias)
template <int EPI, int BIG>
__global__ __launch_bounds__(256) void gemm_bf16(const u16* __restrict__ A,
        const u16* __restrict__ BT, const float* __restrict__ bias,
        float* __restrict__ Cf, u16* __restrict__ Cb,
        int M, int N, int K, int ldc,
        const float* __restrict__ modv, int goff, int mstride) {
    constexpr int BM = BIG ? 128 : 64;
    constexpr int MI = 4;
    constexpr int NJ = BIG ? 4 : 2;
    __shared__ __align__(16) u16 As[2][BM * 32];
    __shared__ __align__(16) u16 Bs[2][128 * 32];
    const int tid = threadIdx.x;
    // XCD-aware bijective swizzle (T1): contiguous chunk per XCD
    const int gx = gridDim.x;
    const int nwg = gx * gridDim.y;
    int flat = blockIdx.y * gx + blockIdx.x;
    const int qq = nwg >> 3;
    flat = (flat & 7) * qq + (flat >> 3);
    const int m0 = (flat / gx) * BM, n0 = (flat % gx) * 128;
    const int lane = tid & 63;
    const int wid = tid >> 6;
    const int wm = BIG ? (wid >> 1) * 64 : 0;
    const int wn = BIG ? (wid & 1) * 64 : wid * 32;
    f32x4 acc[MI][NJ] = {};
    const int srow = tid >> 2, sseg = (tid & 3) * 8;
    const u16* Ag = A + (size_t)(m0 + srow) * K + sseg;
    const u16* Bg = BT + (size_t)(n0 + srow) * K + sseg;
    const int lr = lane & 15, lk = (lane >> 4) * 8;
    gload16(Ag, &As[0][tid * 8]);
    if (BIG) gload16(Ag + (size_t)64 * K, &As[0][tid * 8 + 64 * 32]);
    gload16(Bg, &Bs[0][tid * 8]);
    gload16(Bg + (size_t)64 * K, &Bs[0][tid * 8 + 64 * 32]);
    __syncthreads();
    int cur = 0;
    for (int k0 = 0; k0 < K; k0 += 32) {
        if (k0 + 32 < K) {
            const int nb = cur ^ 1, kn = k0 + 32;
            gload16(Ag + kn, &As[nb][tid * 8]);
            if (BIG) gload16(Ag + kn + (size_t)64 * K, &As[nb][tid * 8 + 64 * 32]);
            gload16(Bg + kn, &Bs[nb][tid * 8]);
            gload16(Bg + kn + (size_t)64 * K, &Bs[nb][tid * 8 + 64 * 32]);
        }
        short8v a_f[MI], b_f[NJ];
        #pragma unroll
        for (int i = 0; i < MI; i++)
            a_f[i] = *(const short8v*)&As[cur][(wm + i * 16 + lr) * 32 + lk];
        #pragma unroll
        for (int j = 0; j < NJ; j++)
            b_f[j] = *(const short8v*)&Bs[cur][(wn + j * 16 + lr) * 32 + lk];
        #pragma unroll
        for (int i = 0; i < MI; i++)
            #pragma unroll
            for (int j = 0; j < NJ; j++)
                acc[i][j] = __builtin_amdgcn_mfma_f32_16x16x32_bf16(a_f[i], b_f[j], acc[i][j], 0, 0, 0);
        __syncthreads();
        cur ^= 1;
    }
    const int r0 = (lane >> 4) * 4;
    #pragma unroll
    for (int i = 0; i < MI; i++) {
        #pragma unroll
        for (int j = 0; j < NJ; j++) {
            const int col = n0 + wn + j * 16 + lr;
            if (col >= N) continue;
            const int row = m0 + wm + i * 16 + r0;
            const float bv = (EPI == 1 || EPI == 2 || EPI == 4) ? bias[col] : 0.f;
            #pragma unroll
            for (int r = 0; r < 4; r++) {
                float v = acc[i][j][r] + bv;
                if (EPI == 0) {
                    Cb[(size_t)(row + r) * ldc + col] = f2bf(v);
                } else if (EPI == 2) {
                    float xx = v;
                    v = 0.5f * xx * (1.f + tanhf(0.7978845608028654f * (xx + 0.044715f * xx * xx * xx)));
                    Cb[(size_t)(row + r) * ldc + col] = f2bf(v);
                } else if (EPI == 3 || EPI == 4) {
                    const int bb = (row + r) >> 11;   // row / Tv
                    float g = modv[(size_t)bb * mstride + goff + col];
                    Cf[(size_t)(row + r) * ldc + col] += g * v;
                } else {
                    Cf[(size_t)(row + r) * ldc + col] = v;
                }
            }
        }
    }
}

// ---- batched weight convert: f32 [Kmax,N] (per layer) -> bf16 [Npad,Kd] ----
__global__ __launch_bounds__(256) void wt_convert_b(const float* __restrict__ W,
        u16* __restrict__ WT, int Kd, int N, int Kmax, int Npad) {
    const float* Wl = W + (size_t)blockIdx.z * Kmax * N;
    u16* WTl = WT + (size_t)blockIdx.z * Npad * Kd;
    __shared__ float t[32][33];
    const int n0 = blockIdx.x * 32, k0 = blockIdx.y * 32;
    const int c = threadIdx.x & 31, rq = (threadIdx.x >> 5) * 4;
    #pragma unroll
    for (int i = 0; i < 4; i++) {
        int n = n0 + c, k = k0 + rq + i;
        t[rq + i][c] = (n < N && k < Kmax) ? Wl[(size_t)k * N + n] : 0.f;
    }
    __syncthreads();
    #pragma unroll
    for (int i = 0; i < 4; i++)
        WTl[(size_t)(n0 + rq + i) * Kd + k0 + c] = f2bf(t[c][rq + i]);
}

// ---- pos-conv weight: w[31][48][768] -> WT[768][1504] bf16 ----
__global__ __launch_bounds__(256) void pw_convert(const float* __restrict__ w,
        u16* __restrict__ WT) {
    __shared__ float t[32][33];
    const int kk0 = blockIdx.x * 32, o0 = blockIdx.y * 32;
    const int c = threadIdx.x & 31, rq = (threadIdx.x >> 5) * 4;
    #pragma unroll
    for (int i = 0; i < 4; i++) {
        int kk = kk0 + rq + i;
        t[rq + i][c] = (kk < 1488) ? w[(size_t)kk * DIMv + o0 + c] : 0.f;
    }
    __syncthreads();
    #pragma unroll
    for (int i = 0; i < 4; i++)
        WT[(size_t)(o0 + rq + i) * PCK + kk0 + c] = f2bf(t[c][rq + i]);
}

// ---- grouped conv K=31 via implicit-im2col MFMA ----
template <int IN_BF, int FUSE>
__global__ __launch_bounds__(256) void posconv_mfma(const void* __restrict__ inv,
        const u16* __restrict__ WT, const float* __restrict__ bias,
        void* __restrict__ outv) {
    __shared__ __align__(16) u16 xs[95 * 48];
    const int t0 = blockIdx.x * 64, g = blockIdx.y, b = blockIdx.z;
    const int tid = threadIdx.x;
    for (int e = tid; e < 95 * 48; e += 256) {
        int rr = e / 48, cc = e % 48;
        int t = t0 - 15 + rr;
        float v = 0.f;
        if (t >= 0 && t < Tv) {
            size_t gi = ((size_t)b * Tv + t) * DIMv + g * 48 + cc;
            v = IN_BF ? bf2f(((const u16*)inv)[gi]) : ((const float*)inv)[gi];
        }
        xs[e] = f2bf(v);
    }
    __syncthreads();
    const int lane = tid & 63, w = tid >> 6;
    const int lr = lane & 15, lq8 = (lane >> 4) * 8, rq = (lane >> 4) * 4;
    const u16* arow = &xs[(w * 16 + lr) * 48 + lq8];
    const u16* brow = &WT[(size_t)(g * 48 + lr) * PCK + lq8];
    f32x4 acc[3] = {};
    #pragma unroll 2
    for (int ks = 0; ks < PCK / 32; ks++) {
        short8v a = *(const short8v*)(arow + ks * 32);
        #pragma unroll
        for (int j = 0; j < 3; j++) {
            short8v bf = *(const short8v*)(brow + (size_t)j * 16 * PCK + ks * 32);
            acc[j] = __builtin_amdgcn_mfma_f32_16x16x32_bf16(a, bf, acc[j], 0, 0, 0);
        }
    }
    #pragma unroll
    for (int j = 0; j < 3; j++) {
        const int o = g * 48 + j * 16 + lr;
        const float bvv = bias[o];
        #pragma unroll
        for (int r = 0; r < 4; r++) {
            const int t = t0 + w * 16 + rq + r;
            float v = acc[j][r] + bvv;
            size_t gi = ((size_t)b * Tv + t) * DIMv + o;
            if (FUSE == 0) ((u16*)outv)[gi] = f2bf(mishf(v));
            else ((float*)outv)[gi] += mishf(v);
        }
    }
}

// ---- time embedding stage 1 ----
__global__ __launch_bounds__(256) void temb1_kernel(const float* __restrict__ timev,
        const float* __restrict__ t_w1, const float* __restrict__ t_b1,
        float* __restrict__ hid) {
    const int b = blockIdx.y;
    const int o = blockIdx.x * 64 + (threadIdx.x & 63);
    const int ks = threadIdx.x >> 6;
    __shared__ float te[256];
    __shared__ float part[4][64];
    {
        int j = threadIdx.x, f = j & 127;
        float fr = expf(-logf(10000.f) / 127.f * (float)f);
        float ang = 1000.f * timev[b] * fr;
        te[j] = (j < 128) ? sinf(ang) : cosf(ang);
    }
    __syncthreads();
    float acc = 0.f;
    #pragma unroll 8
    for (int k = ks * 64; k < ks * 64 + 64; k++) acc += te[k] * t_w1[(size_t)k * DIMv + o];
    part[ks][threadIdx.x & 63] = acc;
    __syncthreads();
    if (threadIdx.x < 64) {
        float r = part[0][threadIdx.x] + part[1][threadIdx.x] + part[2][threadIdx.x] + part[3][threadIdx.x]
                + t_b1[o];
        hid[b * DIMv + o] = siluf(r);
    }
}

// ---- time embedding stage 2 ----
__global__ __launch_bounds__(256) void temb2_kernel(const float* __restrict__ hid,
        const float* __restrict__ t_w2, const float* __restrict__ t_b2,
        float* __restrict__ st_out) {
    const int b = blockIdx.y;
    const int o = blockIdx.x * 64 + (threadIdx.x & 63);
    const int ks = threadIdx.x >> 6;
    __shared__ float hv[DIMv];
    __shared__ float part[4][64];
    for (int j = threadIdx.x; j < DIMv; j += 256) hv[j] = hid[b * DIMv + j];
    __syncthreads();
    float acc = 0.f;
    #pragma unroll 8
    for (int k = ks * 192; k < ks * 192 + 192; k++) acc += hv[k] * t_w2[(size_t)k * DIMv + o];
    part[ks][threadIdx.x & 63] = acc;
    __syncthreads();
    if (threadIdx.x < 64) {
        float r = part[0][threadIdx.x] + part[1][threadIdx.x] + part[2][threadIdx.x] + part[3][threadIdx.x]
                + t_b2[o];
        st_out[b * DIMv + o] = siluf(r);
    }
}

// ---- batched modulation vectors ----
__global__ __launch_bounds__(256) void modvec_kernel(const float* __restrict__ st,
        const float* __restrict__ W, const float* __restrict__ bias,
        float* __restrict__ out, int N) {
    const int l = blockIdx.z, b = blockIdx.y;
    const int o = blockIdx.x * 64 + (threadIdx.x & 63);
    const int ks = threadIdx.x >> 6;
    __shared__ float sv[DIMv];
    __shared__ float part[4][64];
    for (int j = threadIdx.x; j < DIMv; j += 256) sv[j] = st[b * DIMv + j];
    __syncthreads();
    const float* Wl = W + (size_t)l * DIMv * N + o;
    float acc = 0.f;
    #pragma unroll 8
    for (int k = ks * 192; k < ks * 192 + 192; k++) acc += sv[k] * Wl[(size_t)k * N];
    part[ks][threadIdx.x & 63] = acc;
    __syncthreads();
    if (threadIdx.x < 64) {
        float r = part[0][threadIdx.x] + part[1][threadIdx.x] + part[2][threadIdx.x] + part[3][threadIdx.x]
                + bias[(size_t)l * N + o];
        out[((size_t)l * Bv + b) * N + o] = r;
    }
}

// ---- concat [x, cond, temb] -> bf16, K-padded to 736 ----
__global__ void concat_bf16(const float* __restrict__ x, const float* __restrict__ cond,
                            const float* __restrict__ table, const int* __restrict__ text,
                            u16* __restrict__ cat) {
    size_t i = (size_t)blockIdx.x * 256 + threadIdx.x;
    const size_t total = (size_t)Bv * Tv * KCAT;
    if (i >= total) return;
    int j = (int)(i % KCAT);
    size_t row = i / KCAT;
    int t = (int)(row % Tv), b = (int)(row / Tv);
    float v = 0.f;
    if (j < MELv) v = x[row * MELv + j];
    else if (j < 2 * MELv) v = cond[row * MELv + (j - MELv)];
    else if (j < 712) {
        int idx = (t < NTv) ? (text[b * NTv + t] + 1) : 0;
        v = table[(size_t)idx * TDIMv + (j - 2 * MELv)];
    }
    cat[i] = f2bf(v);
}

// ---- LayerNorm with adaLN modulation; BF=1 writes bf16 ----
template <int BF>
__global__ __launch_bounds__(256) void ln_mod_kernel(const float* __restrict__ h,
        void* __restrict__ outv, const float* __restrict__ modv,
        int sc_off, int sh_off, int mod_stride) {
    const int row = blockIdx.x;
    const int b = row / Tv;
    const float* hr = h + (size_t)row * DIMv;
    float s = 0.f;
    for (int j = threadIdx.x; j < DIMv; j += 256) s += hr[j];
    s = blockReduceSum(s);
    const float m = s / DIMv;
    float v = 0.f;
    for (int j = threadIdx.x; j < DIMv; j += 256) { float d = hr[j] - m; v += d * d; }
    v = blockReduceSum(v);
    const float rstd = rsqrtf(v / DIMv + 1e-6f);
    const float* mb = modv + (size_t)b * mod_stride;
    for (int j = threadIdx.x; j < DIMv; j += 256) {
        float val = (hr[j] - m) * rstd * (1.f + mb[sc_off + j]) + mb[sh_off + j];
        if (BF) ((u16*)outv)[(size_t)row * DIMv + j] = f2bf(val);
        else ((float*)outv)[(size_t)row * DIMv + j] = val;
    }
}

// ---- dwconv for B/C channels only (256 ch), bf16 in/out ----
__global__ void dwconv_bc(const u16* __restrict__ zxb, const float* __restrict__ cw,
                          const float* __restrict__ cb, u16* __restrict__ xbcBC) {
    size_t i = (size_t)blockIdx.x * 256 + threadIdx.x;
    const size_t total = (size_t)Bv * Tv * 32;   // 256/8 chunks per row
    if (i >= total) return;
    const int c8 = (int)(i & 31) * 8;
    const size_t row = i >> 5;
    const int t = (int)(row % Tv);
    const u16* base = zxb + row * DINP + DINNER + c8;
    float acc[8];
    #pragma unroll
    for (int u = 0; u < 8; u++) acc[u] = cb[DINNER + c8 + u];
    #pragma unroll
    for (int k = 0; k < KCONVv; k++) {
        const int d = k - 3;
        if (t + d < 0) continue;
        short8v tv = *(const short8v*)(base + (ptrdiff_t)d * DINP);
        #pragma unroll
        for (int u = 0; u < 8; u++)
            acc[u] += bf2fs(tv[u]) * cw[(DINNER + c8 + u) * KCONVv + k];
    }
    short8v outv;
    #pragma unroll
    for (int u = 0; u < 8; u++) outv[u] = (short)f2bf(siluf(acc[u]));
    *(short8v*)(xbcBC + row * 256 + c8) = outv;
}

// ---- dwconv for x channels, writing TRANSPOSED xT[bc][p][s] (bf16) ----
__global__ __launch_bounds__(256) void dwconvT(const u16* __restrict__ zxb,
        const float* __restrict__ cw, const float* __restrict__ cb,
        u16* __restrict__ xT) {
    __shared__ __align__(16) u16 in_s[67 * 72];   // [s'][p], s' <-> t = c*64 + s' - 3
    const int pb = blockIdx.x;        // 0..23 (64 channels each)
    const int c = blockIdx.y, b = blockIdx.z;
    const int bc = b * CNv + c;
    const int tid = threadIdx.x;
    for (int e = tid; e < 67 * 8; e += 256) {
        int sp = e >> 3, p8 = (e & 7) * 8;
        int t = c * 64 + sp - 3;
        short8v v = {};
        if (t >= 0)
            v = *(const short8v*)&zxb[((size_t)b * Tv + t) * DINP + DINNER + pb * 64 + p8];
        *(short8v*)&in_s[sp * 72 + p8] = v;
    }
    __syncthreads();
    const int p = tid >> 2, sb = (tid & 3) * 16;
    const int ch = pb * 64 + p;
    const float w0 = cw[ch * 4], w1 = cw[ch * 4 + 1], w2 = cw[ch * 4 + 2], w3 = cw[ch * 4 + 3];
    const float bb = cb[ch];
    short8v o0, o1;
    #pragma unroll
    for (int i = 0; i < 16; i++) {
        int s = sb + i;
        float acc = bb + bf2f(in_s[s * 72 + p]) * w0 + bf2f(in_s[(s + 1) * 72 + p]) * w1
                  + bf2f(in_s[(s + 2) * 72 + p]) * w2 + bf2f(in_s[(s + 3) * 72 + p]) * w3;
        short r = (short)f2bf(siluf(acc));
        if (i < 8) o0[i] = r; else o1[i - 8] = r;
    }
    u16* dst = xT + ((size_t)bc * DINNER + ch) * 64 + sb;
    *(short8v*)dst = o0;
    *(short8v*)(dst + 8) = o1;
}

// ---- SSD: CB[q][s] = C.B^T (f32) and BTg[n][s] = B^T (bf16), per (b,c) ----
__global__ __launch_bounds__(256) void ssd_cb(const u16* __restrict__ xbcBC,
        float* __restrict__ CBg, u16* __restrict__ BTg) {
    constexpr int ST = 136;
    __shared__ __align__(16) u16 Cs[64 * ST];
    __shared__ __align__(16) u16 Bs[64 * ST];
    const int c = blockIdx.x, b = blockIdx.y;
    const int bc = b * CNv + c;
    const int tid = threadIdx.x;
    const size_t rowbase = (size_t)b * Tv + (size_t)c * QQv;
    for (int e = tid; e < 64 * 16; e += 256) {
        int r = e >> 4, n8 = (e & 15) * 8;
        const u16* src = &xbcBC[(rowbase + r) * 256];
        *(short8v*)&Bs[r * ST + n8] = *(const short8v*)(src + n8);
        *(short8v*)&Cs[r * ST + n8] = *(const short8v*)(src + NSv + n8);
    }
    __syncthreads();
    // transposed B to global (shared by all 24 heads in part1)
    u16* btg = BTg + (size_t)bc * (NSv * QQv);
    for (int e = tid; e < 128 * 64; e += 256) {
        int n = e >> 6, s = e & 63;
        btg[e] = Bs[s * ST + n];
    }
    const int lane = tid & 63, w = tid >> 6;
    const int lr = lane & 15, lk8 = (lane >> 4) * 8, rq = (lane >> 4) * 4;
    f32x4 acc[4] = {};
    #pragma unroll
    for (int ks = 0; ks < 4; ks++) {
        short8v a = *(const short8v*)&Cs[(w * 16 + lr) * ST + ks * 32 + lk8];
        #pragma unroll
        for (int j = 0; j < 4; j++) {
            short8v bf = *(const short8v*)&Bs[(j * 16 + lr) * ST + ks * 32 + lk8];
            acc[j] = __builtin_amdgcn_mfma_f32_16x16x32_bf16(a, bf, acc[j], 0, 0, 0);
        }
    }
    float* out = CBg + (size_t)bc * 4096;
    #pragma unroll
    for (int j = 0; j < 4; j++)
        #pragma unroll
        for (int r = 0; r < 4; r++)
            out[(w * 16 + rq + r) * 64 + j * 16 + lr] = acc[j][r];
}

// ---- SSD part1: scan; y_in = Wsm' @ xT^T; S = (xT.dtrev) @ B ----
__global__ __launch_bounds__(256) void ssd_part1m(const u16* __restrict__ xT,
        const u16* __restrict__ BTg, const u16* __restrict__ zxb,
        const float* __restrict__ dt_bias, const float* __restrict__ A_log,
        const float* __restrict__ CBg, u16* __restrict__ ybuf,
        float* __restrict__ Sg, float* __restrict__ acg, float* __restrict__ atg) {
    constexpr int ST64 = 72;
    __shared__ __align__(16) u16 xTs[64 * ST64];   // [p][s]
    __shared__ __align__(16) u16 Wsm[64 * ST64];   // [q][s]  (cb*exp*dt)
    __shared__ __align__(16) u16 BTs[128 * ST64];  // [n][s]  (B^T * dt*erev)
    __shared__ float ac[64], dts[64], dtrev[64];
    const int h = blockIdx.x, c = blockIdx.y, b = blockIdx.z;
    const int bc = b * CNv + c;
    const int tid = threadIdx.x;
    const size_t rowbase = (size_t)b * Tv + (size_t)c * QQv;
    const size_t bch = ((size_t)bc) * NHv + h;
    if (tid < 64) {
        float raw = bf2f(zxb[(rowbase + tid) * DINP + DINNER + CONVD + h]) + dt_bias[h];
        float dtv = softplusf(raw);
        dts[tid] = dtv;
        float v = dtv * (-expf(A_log[h]));
        #pragma unroll
        for (int off = 1; off < 64; off <<= 1) {
            float t = __shfl_up(v, off, 64);
            if (tid >= off) v += t;
        }
        ac[tid] = v;
        float v63 = __shfl(v, 63, 64);
        dtrev[tid] = dtv * expf(v63 - v);
        acg[bch * 64 + tid] = v;
        if (tid == 63) atg[bch] = expf(v63);
    }
    {
        const u16* src = xT + ((size_t)bc * DINNER + h * PHv) * 64;
        for (int e = tid; e < 64 * 8; e += 256) {
            int p = e >> 3, s8 = (e & 7) * 8;
            *(short8v*)&xTs[p * ST64 + s8] = *(const short8v*)(src + p * 64 + s8);
        }
    }
    __syncthreads();
    {
        const u16* btg = BTg + (size_t)bc * (NSv * QQv);
        for (int e = tid; e < 128 * 8; e += 256) {
            int n = e >> 3, s8 = (e & 7) * 8;
            short8v v = *(const short8v*)(btg + n * 64 + s8);
            short8v o;
            #pragma unroll
            for (int u = 0; u < 8; u++)
                o[u] = (short)f2bf(bf2fs(v[u]) * dtrev[s8 + u]);
            *(short8v*)&BTs[n * ST64 + s8] = o;
        }
        const float* cbrow = CBg + (size_t)bc * 4096;
        for (int e = tid; e < 1024; e += 256) {
            int q = e >> 4, s4 = (e & 15) * 4;
            f32x4 cb4 = *(const f32x4*)&cbrow[q * 64 + s4];
            float aq = ac[q];
            #pragma unroll
            for (int u = 0; u < 4; u++) {
                int s = s4 + u;
                float wv = (s <= q) ? cb4[u] * expf(aq - ac[s]) * dts[s] : 0.f;
                Wsm[q * ST64 + s] = f2bf(wv);
            }
        }
    }
    __syncthreads();
    const int lane = tid & 63, w = tid >> 6;
    const int lr = lane & 15, lk8 = (lane >> 4) * 8, rq = (lane >> 4) * 4;
    // y_in[q][p]
    {
        f32x4 acc[4] = {};
        #pragma unroll
        for (int ks = 0; ks < 2; ks++) {
            short8v bf = *(const short8v*)&xTs[(w * 16 + lr) * ST64 + ks * 32 + lk8];
            #pragma unroll
            for (int i = 0; i < 4; i++) {
                short8v a = *(const short8v*)&Wsm[(i * 16 + lr) * ST64 + ks * 32 + lk8];
                acc[i] = __builtin_amdgcn_mfma_f32_16x16x32_bf16(a, bf, acc[i], 0, 0, 0);
            }
        }
        #pragma unroll
        for (int i = 0; i < 4; i++)
            #pragma unroll
            for (int r = 0; r < 4; r++) {
                int q = i * 16 + rq + r, p = w * 16 + lr;
                ybuf[(rowbase + q) * DINNER + h * PHv + p] = f2bf(acc[i][r]);
            }
    }
    // S[p][n]
    {
        f32x4 acc[4][2] = {};
        #pragma unroll
        for (int ks = 0; ks < 2; ks++) {
            short8v a[4];
            #pragma unroll
            for (int i = 0; i < 4; i++)
                a[i] = *(const short8v*)&xTs[(i * 16 + lr) * ST64 + ks * 32 + lk8];
            #pragma unroll
            for (int j = 0; j < 2; j++) {
                short8v bf = *(const short8v*)&BTs[(w * 32 + j * 16 + lr) * ST64 + ks * 32 + lk8];
                #pragma unroll
                for (int i = 0; i < 4; i++)
                    acc[i][j] = __builtin_amdgcn_mfma_f32_16x16x32_bf16(a[i], bf, acc[i][j], 0, 0, 0);
            }
        }
        float* So = Sg + bch * (PHv * NSv);
        #pragma unroll
        for (int i = 0; i < 4; i++)
            #pragma unroll
            for (int j = 0; j < 2; j++)
                #pragma unroll
                for (int r = 0; r < 4; r++)
                    So[(i * 16 + rq + r) * NSv + w * 32 + j * 16 + lr] = acc[i][j][r];
    }
}

// ---- inter-chunk scan ----
__global__ void ssd_scan(float* __restrict__ Sg, const float* __restrict__ atg) {
    int idx = blockIdx.x * 256 + threadIdx.x;
    if (idx >= Bv * NHv * PHv * NSv) return;
    int n = idx % NSv;
    int p = (idx / NSv) % PHv;
    int h = (idx / (NSv * PHv)) % NHv;
    int b = idx / (NSv * PHv * NHv);
    float H = 0.f;
    for (int c = 0; c < CNv; c++) {
        size_t bch = ((size_t)b * CNv + c) * NHv + h;
        size_t off = bch * PHv * NSv + (size_t)p * NSv + n;
        float s = Sg[off];
        float at = atg[bch];
        Sg[off] = H;
        H = at * H + s;
    }
}

// ---- SSD part2: y += (C @ prev^T)*eac + D*x ----
__global__ __launch_bounds__(256) void ssd_part2m(const u16* __restrict__ xbcBC,
        const u16* __restrict__ xT, const float* __restrict__ Sg,
        const float* __restrict__ acg, const float* __restrict__ Dp,
        u16* __restrict__ ybuf) {
    constexpr int ST = 136;
    __shared__ __align__(16) u16 Cs[64 * ST];
    __shared__ __align__(16) u16 Ps[64 * ST];
    __shared__ float eac[64];
    const int h = blockIdx.x, c = blockIdx.y, b = blockIdx.z;
    const int bc = b * CNv + c;
    const int tid = threadIdx.x;
    const size_t rowbase = (size_t)b * Tv + (size_t)c * QQv;
    const size_t bch = ((size_t)bc) * NHv + h;
    if (tid < 64) eac[tid] = expf(acg[bch * 64 + tid]);
    for (int e = tid; e < 64 * 16; e += 256) {
        int r = e >> 4, n8 = (e & 15) * 8;
        *(short8v*)&Cs[r * ST + n8] =
            *(const short8v*)&xbcBC[(rowbase + r) * 256 + NSv + n8];
        const float* src = &Sg[bch * (PHv * NSv) + (size_t)r * NSv + n8];
        f32x4 a = *(const f32x4*)src, b4 = *(const f32x4*)(src + 4);
        short8v o;
        o[0] = (short)f2bf(a[0]); o[1] = (short)f2bf(a[1]);
        o[2] = (short)f2bf(a[2]); o[3] = (short)f2bf(a[3]);
        o[4] = (short)f2bf(b4[0]); o[5] = (short)f2bf(b4[1]);
        o[6] = (short)f2bf(b4[2]); o[7] = (short)f2bf(b4[3]);
        *(short8v*)&Ps[r * ST + n8] = o;
    }
    __syncthreads();
    const int lane = tid & 63, w = tid >> 6;
    const int lr = lane & 15, lk8 = (lane >> 4) * 8, rq = (lane >> 4) * 4;
    f32x4 acc[4] = {};
    #pragma unroll
    for (int ks = 0; ks < 4; ks++) {
        short8v bf = *(const short8v*)&Ps[(w * 16 + lr) * ST + ks * 32 + lk8];
        #pragma unroll
        for (int i = 0; i < 4; i++) {
            short8v a = *(const short8v*)&Cs[(i * 16 + lr) * ST + ks * 32 + lk8];
            acc[i] = __builtin_amdgcn_mfma_f32_16x16x32_bf16(a, bf, acc[i], 0, 0, 0);
        }
    }
    const float Dh = Dp[h];
    const int p = w * 16 + lr;
    const u16* xrow = xT + ((size_t)bc * DINNER + h * PHv + p) * 64;
    #pragma unroll
    for (int i = 0; i < 4; i++)
        #pragma unroll
        for (int r = 0; r < 4; r++) {
            int q = i * 16 + rq + r;
            size_t yi = (rowbase + q) * DINNER + h * PHv + p;
            float xv = bf2f(xrow[q]);
            ybuf[yi] = f2bf(bf2f(ybuf[yi]) + acc[i][r] * eac[q] + Dh * xv);
        }
}

// ---- gate by silu(z), RMS norm, * rms_w (bf16 in/out) ----
__global__ __launch_bounds__(256) void gate_rms_kernel(const u16* __restrict__ y,
        const u16* __restrict__ zxb, const float* __restrict__ rms_w,
        u16* __restrict__ yb) {
    const int row = blockIdx.x;
    const u16* yr = y + (size_t)row * DINNER;
    const u16* zr = zxb + (size_t)row * DINP;
    float vals[8];
    float ss = 0.f;
    const int tid = threadIdx.x;
    if (tid < 192) {
        short8v yv = *(const short8v*)(yr + tid * 8);
        short8v zv = *(const short8v*)(zr + tid * 8);
        #pragma unroll
        for (int u = 0; u < 8; u++) {
            float v = bf2fs(yv[u]) * siluf(bf2fs(zv[u]));
            vals[u] = v;
            ss += v * v;
        }
    }
    ss = blockReduceSum(ss);
    const float scale = rsqrtf(ss / DINNER + 1e-5f);
    if (tid < 192) {
        short8v outv;
        #pragma unroll
        for (int u = 0; u < 8; u++)
            outv[u] = (short)f2bf(vals[u] * scale * rms_w[tid * 8 + u]);
        *(short8v*)(yb + (size_t)row * DINNER + tid * 8) = outv;
    }
}

extern "C" void kernel_launch(void* const* d_in, const int* in_sizes, int n_in,
                              void* d_out, int out_size, void* d_ws, size_t ws_size,
                              hipStream_t stream) {
    int s3 = (in_sizes[3] == Bv * NTv) ? 1 : 0;
    const float* x      = (const float*)d_in[0];
    const float* cond   = (const float*)d_in[1];
    const float* timev  = (const float*)d_in[2];
    const int*   text   = (const int*)(s3 ? d_in[3] : d_in[32]);
    const float* table  = (const float*)d_in[3 + s3];
    const float* inp_w  = (const float*)d_in[4 + s3];
    const float* inp_b  = (const float*)d_in[5 + s3];
    const float* pos_w1 = (const float*)d_in[6 + s3];
    const float* pos_b1 = (const float*)d_in[7 + s3];
    const float* pos_w2 = (const float*)d_in[8 + s3];
    const float* pos_b2 = (const float*)d_in[9 + s3];
    const float* t_w1   = (const float*)d_in[10 + s3];
    const float* t_b1   = (const float*)d_in[11 + s3];
    const float* t_w2   = (const float*)d_in[12 + s3];
    const float* t_b2   = (const float*)d_in[13 + s3];
    const float* adaln_w= (const float*)d_in[14 + s3];
    const float* adaln_b= (const float*)d_in[15 + s3];
    const float* in_w   = (const float*)d_in[16 + s3];
    const float* conv_w = (const float*)d_in[17 + s3];
    const float* conv_b = (const float*)d_in[18 + s3];
    const float* dt_bias= (const float*)d_in[19 + s3];
    const float* A_log  = (const float*)d_in[20 + s3];
    const float* Dp     = (const float*)d_in[21 + s3];
    const float* rms_w  = (const float*)d_in[22 + s3];
    const float* out_w  = (const float*)d_in[23 + s3];
    const float* ff_w1  = (const float*)d_in[24 + s3];
    const float* ff_b1  = (const float*)d_in[25 + s3];
    const float* ff_w2  = (const float*)d_in[26 + s3];
    const float* ff_b2  = (const float*)d_in[27 + s3];
    const float* fin_w  = (const float*)d_in[28 + s3];
    const float* fin_b  = (const float*)d_in[29 + s3];
    const float* proj_w = (const float*)d_in[30 + s3];
    const float* proj_b = (const float*)d_in[31 + s3];

    // ---- workspace layout ----
    float* ws = (float*)d_ws;
    const size_t n_h = (size_t)Bv * Tv * DIMv;
    size_t off = 0;
    auto nx = [&](size_t n) { float* p = ws + off; off += n; return p; };
    float* h_   = nx(n_h);
    float* S_   = nx((size_t)Bv * CNv * NHv * PHv * NSv);
    float* ac_  = nx((size_t)Bv * CNv * NHv * QQv);
    float* at_  = nx((size_t)Bv * CNv * NHv);
    float* CB_  = nx((size_t)Bv * CNv * QQv * QQv);
    float* st_  = nx((size_t)Bv * DIMv);
    float* hid_ = nx((size_t)Bv * DIMv);
    float* mod_ = nx((size_t)DEPTHv * Bv * 6 * DIMv);
    float* fm_  = nx((size_t)Bv * 2 * DIMv);
    off = (off + 15) & ~(size_t)15;
    u16* wtin_  = (u16*)(ws + off);
    u16* wtout_ = wtin_  + (size_t)DEPTHv * 3456 * 768;
    u16* wtff1_ = wtout_ + (size_t)DEPTHv * 768 * 1536;
    u16* wtff2_ = wtff1_ + (size_t)DEPTHv * 1536 * 768;
    u16* wtinp_ = wtff2_ + (size_t)DEPTHv * 768 * 1536;
    u16* wtprj_ = wtinp_ + (size_t)768 * KCAT;
    u16* pwt1_  = wtprj_ + (size_t)128 * 768;
    u16* pwt2_  = pwt1_  + (size_t)768 * PCK;
    u16* zxb_   = pwt2_  + (size_t)768 * PCK;     // 4096x3352
    u16* xbcBC_ = zxb_   + (size_t)4096 * DINP;   // 4096x256
    u16* xT_    = xbcBC_ + (size_t)4096 * 256;    // 64 x 1536 x 64
    u16* BTg_   = xT_    + (size_t)64 * DINNER * 64;  // 64 x 128 x 64
    u16* yb_    = BTg_   + (size_t)64 * NSv * 64; // 4096x1536
    u16* xnb_   = yb_    + (size_t)4096 * 1536;   // 4096x768
    u16* actb_  = xnb_   + (size_t)4096 * 768;    // 4096x1536
    u16* xnb2_  = actb_  + (size_t)4096 * 1536;   // 4096x768
    u16* catb_  = xnb2_  + (size_t)4096 * 768;    // 4096x736

    const int MT = Bv * Tv;

    // ---- batched weight conversions (all layers upfront) ----
    wt_convert_b<<<dim3(3456 / 32, 768 / 32, DEPTHv), 256, 0, stream>>>(
        in_w, wtin_, 768, DINP, DIMv, 3456);
    wt_convert_b<<<dim3(768 / 32, 1536 / 32, DEPTHv), 256, 0, stream>>>(
        out_w, wtout_, 1536, DIMv, DINNER, 768);
    wt_convert_b<<<dim3(1536 / 32, 768 / 32, DEPTHv), 256, 0, stream>>>(
        ff_w1, wtff1_, 768, FFIv, DIMv, 1536);
    wt_convert_b<<<dim3(768 / 32, 1536 / 32, DEPTHv), 256, 0, stream>>>(
        ff_w2, wtff2_, 1536, DIMv, FFIv, 768);
    wt_convert_b<<<dim3(768 / 32, KCAT / 32, 1), 256, 0, stream>>>(
        inp_w, wtinp_, KCAT, DIMv, 712, 768);
    wt_convert_b<<<dim3(128 / 32, 768 / 32, 1), 256, 0, stream>>>(
        proj_w, wtprj_, 768, MELv, DIMv, 128);
    pw_convert<<<dim3(PCK / 32, DIMv / 32), 256, 0, stream>>>(pos_w1, pwt1_);
    pw_convert<<<dim3(PCK / 32, DIMv / 32), 256, 0, stream>>>(pos_w2, pwt2_);

    // time embedding + modulation vectors
    temb1_kernel<<<dim3(DIMv / 64, Bv), 256, 0, stream>>>(timev, t_w1, t_b1, hid_);
    temb2_kernel<<<dim3(DIMv / 64, Bv), 256, 0, stream>>>(hid_, t_w2, t_b2, st_);
    modvec_kernel<<<dim3(6 * DIMv / 64, Bv, DEPTHv), 256, 0, stream>>>(st_, adaln_w, adaln_b, mod_, 6 * DIMv);
    modvec_kernel<<<dim3(2 * DIMv / 64, Bv, 1), 256, 0, stream>>>(st_, fin_w, fin_b, fm_, 2 * DIMv);

    // input concat + projection
    concat_bf16<<<(unsigned)(((size_t)Bv * Tv * KCAT + 255) / 256), 256, 0, stream>>>(
        x, cond, table, text, catb_);
    gemm_bf16<1, 0><<<dim3(6, 64), 256, 0, stream>>>(
        catb_, wtinp_, inp_b, h_, nullptr, MT, DIMv, KCAT, DIMv, nullptr, 0, 0);

    // pos-conv block
    posconv_mfma<0, 0><<<dim3(Tv / 64, 16, Bv), 256, 0, stream>>>(h_, pwt1_, pos_b1, xnb2_);
    posconv_mfma<1, 1><<<dim3(Tv / 64, 16, Bv), 256, 0, stream>>>(xnb2_, pwt2_, pos_b2, h_);

    for (int l = 0; l < DEPTHv; l++) {
        const float* modl = mod_ + (size_t)l * Bv * 6 * DIMv;
        const float* cwl = conv_w + (size_t)l * CONVD * KCONVv;
        const float* cbl = conv_b + (size_t)l * CONVD;
        // ---- MSA/SSD branch ----
        ln_mod_kernel<1><<<MT, 256, 0, stream>>>(h_, xnb_, modl, DIMv, 0, 6 * DIMv);
        gemm_bf16<0, 1><<<dim3(27, 32), 256, 0, stream>>>(
            xnb_, wtin_ + (size_t)l * 3456 * 768, nullptr, nullptr, zxb_,
            MT, DINP, DIMv, DINP, nullptr, 0, 0);
        dwconv_bc<<<(unsigned)(((size_t)Bv * Tv * 32 + 255) / 256), 256, 0, stream>>>(
            zxb_, cwl, cbl, xbcBC_);
        dwconvT<<<dim3(DINNER / 64, CNv, Bv), 256, 0, stream>>>(zxb_, cwl, cbl, xT_);
        ssd_cb<<<dim3(CNv, Bv), 256, 0, stream>>>(xbcBC_, CB_, BTg_);
        ssd_part1m<<<dim3(NHv, CNv, Bv), 256, 0, stream>>>(
            xT_, BTg_, zxb_, dt_bias + l * NHv, A_log + l * NHv, CB_, yb_, S_, ac_, at_);
        ssd_scan<<<(Bv * NHv * PHv * NSv + 255) / 256, 256, 0, stream>>>(S_, at_);
        ssd_part2m<<<dim3(NHv, CNv, Bv), 256, 0, stream>>>(
            xbcBC_, xT_, S_, ac_, Dp + l * NHv, yb_);
        gate_rms_kernel<<<MT, 256, 0, stream>>>(yb_, zxb_, rms_w + (size_t)l * DINNER, actb_);
        gemm_bf16<3, 0><<<dim3(6, 64), 256, 0, stream>>>(
            actb_, wtout_ + (size_t)l * 768 * 1536, nullptr, h_, nullptr,
            MT, DIMv, DINNER, DIMv, modl, 2 * DIMv, 6 * DIMv);
        // ---- MLP branch ----
        ln_mod_kernel<1><<<MT, 256, 0, stream>>>(h_, xnb_, modl, 4 * DIMv, 3 * DIMv, 6 * DIMv);
        gemm_bf16<2, 1><<<dim3(12, 32), 256, 0, stream>>>(
            xnb_, wtff1_ + (size_t)l * 1536 * 768, ff_b1 + (size_t)l * FFIv, nullptr, actb_,
            MT, FFIv, DIMv, FFIv, nullptr, 0, 0);
        gemm_bf16<4, 0><<<dim3(6, 64), 256, 0, stream>>>(
            actb_, wtff2_ + (size_t)l * 768 * 1536, ff_b2 + (size_t)l * DIMv, h_, nullptr,
            MT, DIMv, FFIv, DIMv, modl, 5 * DIMv, 6 * DIMv);
    }

    // final modulated LN + projection
    ln_mod_kernel<1><<<MT, 256, 0, stream>>>(h_, xnb_, fm_, 0, DIMv, 2 * DIMv);
    gemm_bf16<1, 0><<<dim3(1, 64), 256, 0, stream>>>(
        xnb_, wtprj_, proj_b, (float*)d_out, nullptr, MT, MELv, DIMv, MELv, nullptr, 0, 0);
}